// Round 17
// baseline (1151.777 us; speedup 1.0000x reference)
//
#include <hip/hip_runtime.h>
#include <math.h>

#define Bb 4
#define Tt 512
#define Ee 1024
#define Hh 16
#define Dd 64
#define Ff 4096
#define Mm (Bb*Tt)   // 2048
static constexpr float EPS = 1e-5f;

typedef __attribute__((ext_vector_type(4))) float f32x4;
typedef _Float16 f16;
typedef __attribute__((ext_vector_type(8))) _Float16 f16x8;

// async global->LDS, 16B per lane. LDS dest must be lane-linear.
__device__ __forceinline__ void gload16(const void* g, void* l) {
  __builtin_amdgcn_global_load_lds(
      (const __attribute__((address_space(1))) unsigned int*)g,
      (__attribute__((address_space(3))) unsigned int*)l, 16, 0, 0);
}
__device__ __forceinline__ void wait_vm6() { asm volatile("s_waitcnt vmcnt(6)" ::: "memory"); }
__device__ __forceinline__ void wait_vm4() { asm volatile("s_waitcnt vmcnt(4)" ::: "memory"); }
__device__ __forceinline__ void wait_vm3() { asm volatile("s_waitcnt vmcnt(3)" ::: "memory"); }
__device__ __forceinline__ void wait_vm0() { asm volatile("s_waitcnt vmcnt(0)" ::: "memory"); }

// ---------------------------------------------------------------------------
// FF1: 1-pass fp16 GEMM, 128x128 (r10-r16 math), now 3-buffer 2-deep
// prefetch with counted vmcnt(4) + raw barriers (T4). 48KB LDS.
// ---------------------------------------------------------------------------
__global__ __launch_bounds__(256)
void gemm_f16_128(const f16* __restrict__ A, const f16* __restrict__ W,
                  const float* __restrict__ bias,
                  f16* __restrict__ C, int ldc, int K)
{
  __shared__ f16 AS[3][128][32], BS[3][128][32];
  const int tid = threadIdx.x;
  const int lane = tid & 63, w = tid >> 6;
  const int wr = w >> 1, wc = w & 1;
  const int lhi = lane >> 4, llo = lane & 15;
  const int n0 = blockIdx.x * 128, m0 = blockIdx.y * 128;
  const int s_row = tid >> 2, s_ko = (tid & 3) * 8;

  auto stage = [&](int k0, int buf) {   // 4 loads
#pragma unroll
    for (int i = 0; i < 2; ++i) {
      const int row = s_row + i * 64;
      gload16(&A[(size_t)(m0 + row) * K + k0 + s_ko], &AS[buf][row][s_ko]);
      gload16(&W[(size_t)(n0 + row) * K + k0 + s_ko], &BS[buf][row][s_ko]);
    }
  };

  f32x4 acc[4][4] = {};
  const int nt = K / 32;
  stage(0, 0);
  stage(32, 1);
  wait_vm4();
  __builtin_amdgcn_s_barrier();
  for (int t = 0; t < nt; ++t) {
    const int cur = t % 3;
    if (t + 2 < nt) stage((t + 2) * 32, (t + 2) % 3);
    f16x8 af[4], bf[4];
#pragma unroll
    for (int f = 0; f < 4; ++f) {
      af[f] = *(const f16x8*)&AS[cur][wr * 64 + f * 16 + llo][lhi * 8];
      bf[f] = *(const f16x8*)&BS[cur][wc * 64 + f * 16 + llo][lhi * 8];
    }
#pragma unroll
    for (int m = 0; m < 4; ++m)
#pragma unroll
      for (int n = 0; n < 4; ++n)
        acc[m][n] = __builtin_amdgcn_mfma_f32_16x16x32_f16(af[m], bf[n], acc[m][n], 0, 0, 0);
    if (t + 1 < nt) {
      if (t + 2 < nt) wait_vm4(); else wait_vm0();
      __builtin_amdgcn_s_barrier();
    }
  }

#pragma unroll
  for (int n = 0; n < 4; ++n) {
    const int col = n0 + wc * 64 + n * 16 + llo;
    const float bv = bias[col];
#pragma unroll
    for (int m = 0; m < 4; ++m) {
      const int rbase = m0 + wr * 64 + m * 16 + lhi * 4;
#pragma unroll
      for (int j = 0; j < 4; ++j) {
        float v = fmaxf(acc[m][n][j] + bv, 0.f);
        C[(size_t)(rbase + j) * ldc + col] = (f16)v;
      }
    }
  }
}

// ---------------------------------------------------------------------------
// 1-pass fp16 GEMM, 64x128 (r10-r16 math): FF2 (SPLITK) / final (CONCAT).
// 3-buffer 2-deep prefetch, counted vmcnt(3) + raw barriers. 36KB LDS.
// ---------------------------------------------------------------------------
template<bool CONCAT>
__global__ __launch_bounds__(256)
void gemm_f16_1p(const f16* __restrict__ A, const f16* __restrict__ A2,
                 const f16* __restrict__ W,
                 float* __restrict__ Cf, float* __restrict__ Cf1,
                 int ldc, int K)
{
  __shared__ f16 AS[3][64][32], BS[3][128][32];
  const int tid = threadIdx.x;
  const int lane = tid & 63, w = tid >> 6;
  const int wr = w >> 1, wc = w & 1;
  const int lhi = lane >> 4, llo = lane & 15;
  const int n0 = blockIdx.x * 128;
  const int m0 = blockIdx.y * 64;
  const int half = K >> 1;
  const int kbeg = blockIdx.z * half;
  const int nt = half / 32;
  if (blockIdx.z == 1) Cf = Cf1;

  const int s_row = tid >> 2, s_ko = (tid & 3) * 8;

  auto stage = [&](int k0, int buf) {   // 3 loads
    const int gk = k0 + s_ko;
    const f16* s = A;
    size_t g;
    if (CONCAT) {
      if (gk < Ee) { g = (size_t)(m0 + s_row) * Ee + gk; }
      else { g = (size_t)(m0 + s_row) * Ee + (gk - Ee); s = A2; }
    } else {
      g = (size_t)(m0 + s_row) * K + gk;
    }
    gload16(&s[g], &AS[buf][s_row][s_ko]);
#pragma unroll
    for (int i = 0; i < 2; ++i)
      gload16(&W[(size_t)(n0 + s_row + i * 64) * K + gk], &BS[buf][s_row + i * 64][s_ko]);
  };

  f32x4 acc[2][4] = {};
  stage(kbeg, 0);
  stage(kbeg + 32, 1);
  wait_vm3();
  __builtin_amdgcn_s_barrier();
  for (int t = 0; t < nt; ++t) {
    const int cur = t % 3;
    if (t + 2 < nt) stage(kbeg + (t + 2) * 32, (t + 2) % 3);
    f16x8 af[2], bf[4];
#pragma unroll
    for (int m = 0; m < 2; ++m)
      af[m] = *(const f16x8*)&AS[cur][wr * 32 + m * 16 + llo][lhi * 8];
#pragma unroll
    for (int n = 0; n < 4; ++n)
      bf[n] = *(const f16x8*)&BS[cur][wc * 64 + n * 16 + llo][lhi * 8];
#pragma unroll
    for (int m = 0; m < 2; ++m)
#pragma unroll
      for (int n = 0; n < 4; ++n)
        acc[m][n] = __builtin_amdgcn_mfma_f32_16x16x32_f16(af[m], bf[n], acc[m][n], 0, 0, 0);
    if (t + 1 < nt) {
      if (t + 2 < nt) wait_vm3(); else wait_vm0();
      __builtin_amdgcn_s_barrier();
    }
  }

#pragma unroll
  for (int n = 0; n < 4; ++n) {
    const int col = n0 + wc * 64 + n * 16 + llo;
#pragma unroll
    for (int m = 0; m < 2; ++m) {
      const int rbase = m0 + wr * 32 + m * 16 + lhi * 4;
#pragma unroll
      for (int j = 0; j < 4; ++j)
        Cf[(size_t)(rbase + j) * ldc + col] = acc[m][n][j];
    }
  }
}

// ---------------------------------------------------------------------------
// QKV projection (r11-r16 math): 64x128, grid.x=24, sec = bx>>3.
// Q,K: 3-pass (h,l); V: 1-pass. 3-buffer 2-deep prefetch, counted
// vmcnt(6)/(3) + raw barriers. 72KB LDS.
// ---------------------------------------------------------------------------
__global__ __launch_bounds__(256)
void gemm_qkv(const f16* __restrict__ Ah_g, const f16* __restrict__ Al_g,
              const f16* __restrict__ Wh, const f16* __restrict__ Wl,
              f16* __restrict__ Qh, f16* __restrict__ Ql,
              f16* __restrict__ Kh, f16* __restrict__ Kl,
              f16* __restrict__ Vv)
{
  __shared__ f16 AhS[3][64][32], AlS[3][64][32];
  __shared__ f16 BhS[3][128][32], BlS[3][128][32];
  const int tid = threadIdx.x;
  const int lane = tid & 63, w = tid >> 6;
  const int wr = w >> 1, wc = w & 1;
  const int lhi = lane >> 4, llo = lane & 15;
  const int sec = blockIdx.x >> 3;
  const bool three = (sec < 2);
  const int n0 = (blockIdx.x & 7) * 128;
  Wh += (size_t)sec << 20;
  Wl += (size_t)sec << 20;
  const int m0 = blockIdx.y * 64;
  const int s_row = tid >> 2, s_ko = (tid & 3) * 8;

  auto stage = [&](int k0, int buf) {   // 6 loads (three) or 3 (V)
    const size_t g = (size_t)(m0 + s_row) * Ee + k0 + s_ko;
    gload16(&Ah_g[g], &AhS[buf][s_row][s_ko]);
    if (three) gload16(&Al_g[g], &AlS[buf][s_row][s_ko]);
#pragma unroll
    for (int i = 0; i < 2; ++i) {
      size_t gb = (size_t)(n0 + s_row + i * 64) * Ee + k0 + s_ko;
      gload16(&Wh[gb], &BhS[buf][s_row + i * 64][s_ko]);
      if (three) gload16(&Wl[gb], &BlS[buf][s_row + i * 64][s_ko]);
    }
  };
  auto wait_vmL = [&]() { if (three) wait_vm6(); else wait_vm3(); };

  f32x4 acc[2][4] = {};
  constexpr int nt = Ee / 32;
  stage(0, 0);
  stage(32, 1);
  wait_vmL();
  __builtin_amdgcn_s_barrier();
  for (int t = 0; t < nt; ++t) {
    const int cur = t % 3;
    if (t + 2 < nt) stage((t + 2) * 32, (t + 2) % 3);
    f16x8 ah[2], bh[4];
#pragma unroll
    for (int m = 0; m < 2; ++m)
      ah[m] = *(const f16x8*)&AhS[cur][wr * 32 + m * 16 + llo][lhi * 8];
#pragma unroll
    for (int n = 0; n < 4; ++n)
      bh[n] = *(const f16x8*)&BhS[cur][wc * 64 + n * 16 + llo][lhi * 8];
    if (three) {
      f16x8 al[2], bl[4];
#pragma unroll
      for (int m = 0; m < 2; ++m)
        al[m] = *(const f16x8*)&AlS[cur][wr * 32 + m * 16 + llo][lhi * 8];
#pragma unroll
      for (int n = 0; n < 4; ++n)
        bl[n] = *(const f16x8*)&BlS[cur][wc * 64 + n * 16 + llo][lhi * 8];
#pragma unroll
      for (int m = 0; m < 2; ++m)
#pragma unroll
        for (int n = 0; n < 4; ++n) {
          acc[m][n] = __builtin_amdgcn_mfma_f32_16x16x32_f16(ah[m], bh[n], acc[m][n], 0, 0, 0);
          acc[m][n] = __builtin_amdgcn_mfma_f32_16x16x32_f16(ah[m], bl[n], acc[m][n], 0, 0, 0);
          acc[m][n] = __builtin_amdgcn_mfma_f32_16x16x32_f16(al[m], bh[n], acc[m][n], 0, 0, 0);
        }
    } else {
#pragma unroll
      for (int m = 0; m < 2; ++m)
#pragma unroll
        for (int n = 0; n < 4; ++n)
          acc[m][n] = __builtin_amdgcn_mfma_f32_16x16x32_f16(ah[m], bh[n], acc[m][n], 0, 0, 0);
    }
    if (t + 1 < nt) {
      if (t + 2 < nt) wait_vmL(); else wait_vm0();
      __builtin_amdgcn_s_barrier();
    }
  }

#pragma unroll
  for (int n = 0; n < 4; ++n) {
    const int col = n0 + wc * 64 + n * 16 + llo;
#pragma unroll
    for (int m = 0; m < 2; ++m) {
      const int rbase = m0 + wr * 32 + m * 16 + lhi * 4;
#pragma unroll
      for (int j = 0; j < 4; ++j) {
        const float v = acc[m][n][j];
        const size_t idx = (size_t)(rbase + j) * Ee + col;
        if (sec == 0) {
          f16 h = (f16)v;
          Qh[idx] = h;
          Ql[idx] = (f16)(v - (float)h);
        } else if (sec == 1) {
          f16 h = (f16)v;
          Kh[idx] = h;
          Kl[idx] = (f16)(v - (float)h);
        } else {
          Vv[idx] = (f16)v;
        }
      }
    }
  }
}

// ---------------------------------------------------------------------------
// Split-f16 MFMA flash attention (PROVEN r11-r16, byte-identical), causal.
// ---------------------------------------------------------------------------
__global__ __launch_bounds__(256)
void attn_ms(const f16* __restrict__ Qh_g, const f16* __restrict__ Ql_g,
             const f16* __restrict__ Kh_g, const f16* __restrict__ Kl_g,
             const f16* __restrict__ Vv_g, float* __restrict__ O)
{
  __shared__ f16 Ksh[64][72], Ksl[64][72];   // [s][d]
  __shared__ f16 Vs[64][72];                 // [d][s] (transposed)
  __shared__ f16 Pw[4][16][72];              // per-wave P [q_local][s]
  const int tid = threadIdx.x;
  const int lane = tid & 63, w = tid >> 6;
  const int lhi = lane >> 4, llo = lane & 15;
  const int q0 = blockIdx.x * 64;
  const int bh = blockIdx.y;
  const size_t base = (size_t)(bh >> 4) * Tt * Ee + (size_t)(bh & 15) * Dd;

  f16x8 qfh[2], qfl[2];
#pragma unroll
  for (int ks = 0; ks < 2; ++ks) {
    const size_t qoff = base + (size_t)(q0 + w * 16 + llo) * Ee + ks * 32 + lhi * 8;
    qfh[ks] = *(const f16x8*)&Qh_g[qoff];
    qfl[ks] = *(const f16x8*)&Ql_g[qoff];
  }

  f32x4 oacc[4] = {};
  float m_run[4], l_run[4];
#pragma unroll
  for (int j = 0; j < 4; ++j) { m_run[j] = -INFINITY; l_run[j] = 0.f; }

  for (int s0 = 0; s0 <= q0; s0 += 64) {
#pragma unroll
    for (int pass = 0; pass < 2; ++pass) {
      int c = tid + 256 * pass;
      int row = c >> 3, d0 = (c & 7) * 8;
      const size_t g = base + (size_t)(s0 + row) * Ee + d0;
      f16x8 kh = *(const f16x8*)&Kh_g[g];
      f16x8 kl = *(const f16x8*)&Kl_g[g];
      f16x8 vf = *(const f16x8*)&Vv_g[g];
      *(f16x8*)&Ksh[row][d0] = kh;
      *(f16x8*)&Ksl[row][d0] = kl;
#pragma unroll
      for (int j = 0; j < 8; ++j) Vs[d0 + j][row] = vf[j];
    }
    __syncthreads();

    f32x4 sacc[4] = {};
#pragma unroll
    for (int ks = 0; ks < 2; ++ks)
#pragma unroll
      for (int n = 0; n < 4; ++n) {
        f16x8 kfh = *(const f16x8*)&Ksh[n * 16 + llo][ks * 32 + lhi * 8];
        f16x8 kfl = *(const f16x8*)&Ksl[n * 16 + llo][ks * 32 + lhi * 8];
        sacc[n] = __builtin_amdgcn_mfma_f32_16x16x32_f16(qfh[ks], kfh, sacc[n], 0, 0, 0);
        sacc[n] = __builtin_amdgcn_mfma_f32_16x16x32_f16(qfh[ks], kfl, sacc[n], 0, 0, 0);
        sacc[n] = __builtin_amdgcn_mfma_f32_16x16x32_f16(qfl[ks], kfh, sacc[n], 0, 0, 0);
      }

    if (s0 == q0) {
#pragma unroll
      for (int n = 0; n < 4; ++n)
#pragma unroll
        for (int j = 0; j < 4; ++j)
          if (n * 16 + llo > w * 16 + lhi * 4 + j) sacc[n][j] = -INFINITY;
    }

    float scj[4];
#pragma unroll
    for (int j = 0; j < 4; ++j) {
      float mt = fmaxf(fmaxf(sacc[0][j], sacc[1][j]), fmaxf(sacc[2][j], sacc[3][j]));
#pragma unroll
      for (int off = 1; off < 16; off <<= 1) mt = fmaxf(mt, __shfl_xor(mt, off));
      float mn = fmaxf(m_run[j], mt);
      scj[j] = __expf(m_run[j] - mn);
      m_run[j] = mn;
      float rs = 0.f;
#pragma unroll
      for (int n = 0; n < 4; ++n) {
        float pp = __expf(sacc[n][j] - mn);
        sacc[n][j] = pp;
        rs += pp;
      }
#pragma unroll
      for (int off = 1; off < 16; off <<= 1) rs += __shfl_xor(rs, off);
      l_run[j] = l_run[j] * scj[j] + rs;
    }

#pragma unroll
    for (int n = 0; n < 4; ++n)
#pragma unroll
      for (int j = 0; j < 4; ++j)
        Pw[w][lhi * 4 + j][n * 16 + llo] = (f16)sacc[n][j];
#pragma unroll
    for (int df = 0; df < 4; ++df)
#pragma unroll
      for (int j = 0; j < 4; ++j)
        oacc[df][j] *= scj[j];

#pragma unroll
    for (int ks = 0; ks < 2; ++ks) {
      f16x8 pf = *(const f16x8*)&Pw[w][llo][ks * 32 + lhi * 8];
#pragma unroll
      for (int df = 0; df < 4; ++df) {
        f16x8 vfr = *(const f16x8*)&Vs[df * 16 + llo][ks * 32 + lhi * 8];
        oacc[df] = __builtin_amdgcn_mfma_f32_16x16x32_f16(pf, vfr, oacc[df], 0, 0, 0);
      }
    }
    __syncthreads();
  }

#pragma unroll
  for (int j = 0; j < 4; ++j) {
    float inv = 1.f / l_run[j];
#pragma unroll
    for (int df = 0; df < 4; ++df)
      O[base + (size_t)(q0 + w * 16 + lhi * 4 + j) * Ee + df * 16 + llo] =
          oacc[df][j] * inv;
  }
}

// ---------------------------------------------------------------------------
// Per-head LN over D=64 + residual (PROVEN r11-r16); fp32 + (h,l) f16.
// ---------------------------------------------------------------------------
__global__ __launch_bounds__(256)
void attn_ln_res(const float* __restrict__ O, const float* Yin,
                 const float* __restrict__ g, const float* __restrict__ bta,
                 float* Yout, f16* __restrict__ Yh, f16* __restrict__ Yl)
{
  const int tid = threadIdx.x;
  const int w = (blockIdx.x << 2) + (tid >> 6);
  const int lane = tid & 63;
  const int m = w >> 4;
  const int h = w & 15;
  const size_t idx = (size_t)m * Ee + h * Dd + lane;
  float x = O[idx];
  float s = x, s2 = x * x;
#pragma unroll
  for (int off = 1; off < 64; off <<= 1) {
    s  += __shfl_xor(s, off);
    s2 += __shfl_xor(s2, off);
  }
  float mean = s * (1.f / 64.f);
  float var  = s2 * (1.f / 64.f) - mean * mean;
  float inv  = rsqrtf(var + EPS);
  float r = Yin[idx] + (x - mean) * inv * g[h * Dd + lane] + bta[h * Dd + lane];
  Yout[idx] = r;
  f16 hh = (f16)r;
  Yh[idx] = hh;
  Yl[idx] = (f16)(r - (float)hh);
}

// ---------------------------------------------------------------------------
// Row LN over E=1024 + residual (PROVEN r11-r16). Input = T0 + T1 + bias.
// ---------------------------------------------------------------------------
__global__ __launch_bounds__(256)
void ff_ln_res(const float* __restrict__ T0, const float* __restrict__ T1,
               const float* __restrict__ b2,
               const float* Yin, const float* __restrict__ g,
               const float* __restrict__ bb,
               float* Yout, f16* __restrict__ Yh, f16* __restrict__ Yl)
{
  __shared__ float red[8];
  const int m = blockIdx.x;
  const int tid = threadIdx.x;
  const size_t basep = (size_t)m * Ee;
  float4 xa = *(const float4*)&T0[basep + (tid << 2)];
  float4 xb = *(const float4*)&T1[basep + (tid << 2)];
  float4 bv2 = *(const float4*)&b2[tid << 2];
  float xv[4] = {xa.x + xb.x + bv2.x, xa.y + xb.y + bv2.y,
                 xa.z + xb.z + bv2.z, xa.w + xb.w + bv2.w};
  float s  = xv[0] + xv[1] + xv[2] + xv[3];
  float s2 = xv[0]*xv[0] + xv[1]*xv[1] + xv[2]*xv[2] + xv[3]*xv[3];
#pragma unroll
  for (int off = 1; off < 64; off <<= 1) {
    s  += __shfl_xor(s, off);
    s2 += __shfl_xor(s2, off);
  }
  const int wid = tid >> 6;
  if ((tid & 63) == 0) { red[wid] = s; red[4 + wid] = s2; }
  __syncthreads();
  s  = red[0] + red[1] + red[2] + red[3];
  s2 = red[4] + red[5] + red[6] + red[7];
  float mean = s * (1.f / Ee);
  float var  = s2 * (1.f / Ee) - mean * mean;
  float inv  = rsqrtf(var + EPS);
  float4 y  = *(const float4*)&Yin[basep + (tid << 2)];
  float4 gg = *(const float4*)&g[tid << 2];
  float4 bv = *(const float4*)&bb[tid << 2];
  float gga[4] = {gg.x, gg.y, gg.z, gg.w};
  float bva[4] = {bv.x, bv.y, bv.z, bv.w};
  float ya[4] = {y.x, y.y, y.z, y.w};
  float o[4];
#pragma unroll
  for (int j = 0; j < 4; ++j) {
    o[j] = ya[j] + (xv[j] - mean) * inv * gga[j] + bva[j];
    f16 hh = (f16)o[j];
    Yh[basep + (tid << 2) + j] = hh;
    Yl[basep + (tid << 2) + j] = (f16)(o[j] - (float)hh);
  }
  *(float4*)&Yout[basep + (tid << 2)] = *(float4*)o;
}

// out = p0 + p1 + bias (final linear reduce)
__global__ __launch_bounds__(256)
void add2_bias(const float* __restrict__ p0, const float* __restrict__ p1,
               const float* __restrict__ b, float* __restrict__ out)
{
  const size_t i = ((size_t)blockIdx.x * 256 + threadIdx.x) * 4;
  const int col = (int)(i & (Ee - 1));
  float4 a = *(const float4*)&p0[i];
  float4 c = *(const float4*)&p1[i];
  float4 bb = *(const float4*)&b[col];
  float4 o;
  o.x = a.x + c.x + bb.x; o.y = a.y + c.y + bb.y;
  o.z = a.z + c.z + bb.z; o.w = a.w + c.w + bb.w;
  *(float4*)&out[i] = o;
}

// fp32 -> (hi,lo) f16 split for BOTH branches in one launch (PROVEN r15/r16).
__global__ __launch_bounds__(256)
void split_act2(const float* __restrict__ in,
                f16* __restrict__ oh1, f16* __restrict__ ol1,
                f16* __restrict__ oh2, f16* __restrict__ ol2)
{
  const size_t nb = gridDim.x >> 1;
  size_t bid = blockIdx.x;
  f16 *oh, *ol;
  if (bid < nb) { oh = oh1; ol = ol1; }
  else { bid -= nb; oh = oh2; ol = ol2; }
  const size_t i = (bid * 256 + threadIdx.x) * 4;
  float4 v = *(const float4*)&in[i];
  float f[4] = {v.x, v.y, v.z, v.w};
#pragma unroll
  for (int j = 0; j < 4; ++j) {
    f16 h = (f16)f[j];
    oh[i + j] = h;
    ol[i + j] = (f16)(f[j] - (float)h);
  }
}

// ---------------------------------------------------------------------------
// FAST transpose-convert (PROVEN r16): fp32 [R][C] -> f16 [C][R].
// ---------------------------------------------------------------------------
__device__ __forceinline__ void cvtT_tile(const float* in, f16* outp,
                                          int R, int C, int tx, int ty, int tid)
{
  __shared__ float tile[64][33];
  const int c0 = tx * 32, r0 = ty * 64;
  const int r = tid >> 2, c8 = (tid & 3) * 8;
  const float* src = &in[(size_t)(r0 + r) * C + c0 + c8];
  float4 a = *(const float4*)src;
  float4 b = *(const float4*)(src + 4);
  tile[r][c8 + 0] = a.x; tile[r][c8 + 1] = a.y;
  tile[r][c8 + 2] = a.z; tile[r][c8 + 3] = a.w;
  tile[r][c8 + 4] = b.x; tile[r][c8 + 5] = b.y;
  tile[r][c8 + 6] = b.z; tile[r][c8 + 7] = b.w;
  __syncthreads();
  const int oc = tid >> 3, rr = (tid & 7) * 8;
  f16x8 o;
#pragma unroll
  for (int j = 0; j < 8; ++j) o[j] = (f16)tile[rr + j][oc];
  *(f16x8*)&outp[(size_t)(c0 + oc) * R + r0 + rr] = o;
}

__global__ __launch_bounds__(256)
void cvtT_f16(const float* __restrict__ in, f16* __restrict__ outp, int R, int C)
{
  const int nx = C >> 5;
  cvtT_tile(in, outp, R, C, blockIdx.x % nx, blockIdx.x / nx, threadIdx.x);
}

// Fused FF weight transpose (fast, PROVEN r16).
__global__ __launch_bounds__(256)
void cvtT_ff(const float* __restrict__ w1, const float* __restrict__ w2,
             f16* __restrict__ o1, f16* __restrict__ o2)
{
  constexpr int NT1 = (Ff / 32) * (Ee / 64);   // 2048
  int id = blockIdx.x;
  const float* in; f16* outp; int R, C;
  if (id < NT1) { in = w1; outp = o1; R = Ee; C = Ff; }
  else { id -= NT1; in = w2; outp = o2; R = Ff; C = Ee; }
  const int nx = C >> 5;
  cvtT_tile(in, outp, R, C, id % nx, id / nx, threadIdx.x);
}

// Fast fused QKV weight transpose-split (PROVEN r16).
__global__ __launch_bounds__(256)
void cvtT_qkv(const float* __restrict__ wq, const float* __restrict__ wk,
              const float* __restrict__ wv, f16* __restrict__ out_h,
              f16* __restrict__ out_l)
{
  __shared__ float tile[64][33];
  const int z = blockIdx.z, sec = z >> 4, hh = z & 15;
  const float* in = (sec == 0) ? wq : (sec == 1) ? wk : wv;
  const size_t zi = (size_t)hh * Ee * Dd;
  const size_t zo = ((size_t)sec << 20) + (size_t)hh * Ee * Dd;
  const int c0 = blockIdx.x * 32, r0 = blockIdx.y * 64;
  const int tid = threadIdx.x;
  const int r = tid >> 2, c8 = (tid & 3) * 8;
  const float* src = &in[zi + (size_t)(r0 + r) * Dd + c0 + c8];
  float4 a = *(const float4*)src;
  float4 b = *(const float4*)(src + 4);
  tile[r][c8 + 0] = a.x; tile[r][c8 + 1] = a.y;
  tile[r][c8 + 2] = a.z; tile[r][c8 + 3] = a.w;
  tile[r][c8 + 4] = b.x; tile[r][c8 + 5] = b.y;
  tile[r][c8 + 6] = b.z; tile[r][c8 + 7] = b.w;
  __syncthreads();
  const int oc = tid >> 3, rr = (tid & 7) * 8;
  f16x8 oh, ol;
#pragma unroll
  for (int j = 0; j < 8; ++j) {
    float f = tile[rr + j][oc];
    f16 h = (f16)f;
    oh[j] = h;
    ol[j] = (f16)(f - (float)h);
  }
  const size_t ob = zo + (size_t)(c0 + oc) * Ee + r0 + rr;
  *(f16x8*)&out_h[ob] = oh;
  *(f16x8*)&out_l[ob] = ol;
}

// ---------------------------------------------------------------------------
extern "C" void kernel_launch(void* const* d_in, const int* in_sizes, int n_in,
                              void* d_out, int out_size, void* d_ws, size_t ws_size,
                              hipStream_t stream)
{
  const float* x     = (const float*)d_in[0];
  const float* mh_wq = (const float*)d_in[1];
  const float* mh_wk = (const float*)d_in[2];
  const float* mh_wv = (const float*)d_in[3];
  const float* mh_g  = (const float*)d_in[4];
  const float* mh_b  = (const float*)d_in[5];
  const float* ff_w1 = (const float*)d_in[6];
  const float* ff_b1 = (const float*)d_in[7];
  const float* ff_w2 = (const float*)d_in[8];
  const float* ff_b2 = (const float*)d_in[9];
  const float* ff_g  = (const float*)d_in[10];
  const float* ff_bb = (const float*)d_in[11];
  const float* lt_w  = (const float*)d_in[12];
  const float* lt_b  = (const float*)d_in[13];
  float* out = (float*)d_out;

  // ===== EXACT r11/r15/r16 buffer layout (proven). 88 MB. =====
  const size_t ME = (size_t)Mm * Ee;   // 2M elements
  char* p = (char*)d_ws;
  auto alloc = [&](size_t bytes) { void* r = (void*)p; p += (bytes + 255) & ~(size_t)255; return r; };
  float* bufA  = (float*)alloc(ME * 4);                // 8 MB
  f16*   bufAh = (f16*)alloc(ME * 2);                  // 4 MB
  f16*   bufAl = (f16*)alloc(ME * 2);                  // 4 MB
  float* bufB  = (float*)alloc(ME * 4);                // 8 MB
  f16*   bufBh = (f16*)alloc(ME * 2);                  // 4 MB
  f16*   bufBl = (f16*)alloc(ME * 2);                  // 4 MB
  f16*   wt_h  = (f16*)alloc((size_t)Ff * Ee * 2);     // 8 MB (w1 / qkv-h / lt)
  f16*   wt_l  = (f16*)alloc((size_t)Ff * Ee * 2);     // 8 MB (w2 / qkv-l)
  float* reg   = (float*)alloc((size_t)10 * 1024 * 1024 * 4);  // 40 MB union
  f16*   qh_   = (f16*)reg;
  f16*   ql_   = qh_ + ME;
  f16*   kh_   = qh_ + 2 * ME;
  f16*   kl_   = qh_ + 3 * ME;
  f16*   vv_   = qh_ + 4 * ME;
  float* ob    = reg + 5 * 1024 * 1024;        // attn out (20..28 MB)
  f16*   hid   = (f16*)reg;                    // ff phase: [M,F] f16 = 16 MB
  float* tmp   = reg + 8 * 1024 * 1024;        // fp32 partial (32..40 MB)

  // mh: byte-identical dataflow to r16.
  auto mh = [&](int i, const float* srcF, const f16* srcH, const f16* srcL,
                float* dstF, f16* dstH, f16* dstL) {
    const size_t wo = (size_t)i * Hh * Ee * Dd;
    cvtT_qkv<<<dim3(Dd / 32, Ee / 64, 48), 256, 0, stream>>>(
        mh_wq + wo, mh_wk + wo, mh_wv + wo, wt_h, wt_l);
    gemm_qkv<<<dim3(24, Mm / 64), 256, 0, stream>>>(
        srcH, srcL, wt_h, wt_l, qh_, ql_, kh_, kl_, vv_);
    attn_ms<<<dim3(Tt / 64, Bb * Hh), 256, 0, stream>>>(qh_, ql_, kh_, kl_, vv_, ob);
    attn_ln_res<<<dim3(Mm * Hh / 4), 256, 0, stream>>>(
        ob, srcF, mh_g + (size_t)i * Hh * Dd, mh_b + (size_t)i * Hh * Dd, dstF, dstH, dstL);
  };
  // ff: byte-identical dataflow to r16.
  auto ff = [&](int i, const float* srcF, const f16* srcH,
                float* dstF, f16* dstH, f16* dstL, float* tmp1) {
    cvtT_ff<<<dim3((Ff / 32) * (Ee / 64) + (Ee / 32) * (Ff / 64)), 256, 0, stream>>>(
        ff_w1 + (size_t)i * Ee * Ff, ff_w2 + (size_t)i * Ff * Ee, wt_h, wt_l);
    gemm_f16_128<<<dim3(Ff / 128, Mm / 128), 256, 0, stream>>>(
        srcH, wt_h, ff_b1 + (size_t)i * Ff, hid, Ff, Ee);
    gemm_f16_1p<false><<<dim3(Ee / 128, Mm / 64, 2), 256, 0, stream>>>(
        hid, nullptr, wt_l, tmp, tmp1, Ee, Ff);
    ff_ln_res<<<dim3(Mm), 256, 0, stream>>>(
        tmp, tmp1, ff_b2 + (size_t)i * Ee,
        srcF, ff_g + (size_t)i * Ee, ff_bb + (size_t)i * Ee, dstF, dstH, dstL);
  };

  // both branches' x-split in one launch
  split_act2<<<dim3(2 * ME / 1024), 256, 0, stream>>>(x, bufAh, bufAl, bufBh, bufBl);

  // out_one branch: ff(3, mh(4, mh(0, x)))   [bufB fp32 dead -> tmp1]
  mh(0, x, bufAh, bufAl, bufA, bufAh, bufAl);
  mh(4, bufA, bufAh, bufAl, bufA, bufAh, bufAl);
  ff(3, bufA, bufAh, bufA, bufAh, bufAl, bufB);

  // out_two branch: 3 encoder blocks then decoder  [bufA fp32 dead -> tmp1]
  mh(1, x, bufBh, bufBl, bufB, bufBh, bufBl);
  ff(0, bufB, bufBh, bufB, bufBh, bufBl, bufA);
  mh(2, bufB, bufBh, bufBl, bufB, bufBh, bufBl);
  ff(1, bufB, bufBh, bufB, bufBh, bufBl, bufA);
  mh(3, bufB, bufBh, bufBl, bufB, bufBh, bufBl);
  ff(2, bufB, bufBh, bufB, bufBh, bufBl, bufA);
  mh(4, bufB, bufBh, bufBl, bufB, bufBh, bufBl);
  ff(3, bufB, bufBh, bufB, bufBh, bufBl, bufA);

  // final: out = concat(A,B)@lt_w + lt_b, 1-pass f16, split-K=2 into dead bufs
  cvtT_f16<<<dim3((Ee / 32) * (2 * Ee / 64)), 256, 0, stream>>>(lt_w, wt_h, 2 * Ee, Ee);
  gemm_f16_1p<true><<<dim3(Ee / 128, Mm / 64, 2), 256, 0, stream>>>(
      bufAh, bufBh, wt_h, bufA, bufB, Ee, 2 * Ee);
  add2_bias<<<dim3(ME / 1024), 256, 0, stream>>>(bufA, bufB, lt_b, out);
}

// Round 18
// 1004.463 us; speedup vs baseline: 1.1467x; 1.1467x over previous
//
#include <hip/hip_runtime.h>
#include <math.h>

#define Bb 4
#define Tt 512
#define Ee 1024
#define Hh 16
#define Dd 64
#define Ff 4096
#define Mm (Bb*Tt)   // 2048
static constexpr float EPS = 1e-5f;

typedef __attribute__((ext_vector_type(4))) float f32x4;
typedef _Float16 f16;
typedef __attribute__((ext_vector_type(8))) _Float16 f16x8;

// async global->LDS, 16B per lane. LDS dest must be lane-linear.
__device__ __forceinline__ void gload16(const void* g, void* l) {
  __builtin_amdgcn_global_load_lds(
      (const __attribute__((address_space(1))) unsigned int*)g,
      (__attribute__((address_space(3))) unsigned int*)l, 16, 0, 0);
}

// ---------------------------------------------------------------------------
// FF1: 1-pass fp16 GEMM, m97 structure (PROVEN r10-r16). 128x128, BK=32,
// single-buffer 16KB LDS, gload_lds staging. Bias+ReLU, f16 out.
// ---------------------------------------------------------------------------
__global__ __launch_bounds__(256)
void gemm_f16_128(const f16* __restrict__ A, const f16* __restrict__ W,
                  const float* __restrict__ bias,
                  f16* __restrict__ C, int ldc, int K)
{
  __shared__ f16 AS[128][32], BS[128][32];
  const int tid = threadIdx.x;
  const int lane = tid & 63, w = tid >> 6;
  const int wr = w >> 1, wc = w & 1;
  const int lhi = lane >> 4, llo = lane & 15;
  const int n0 = blockIdx.x * 128, m0 = blockIdx.y * 128;
  const int s_row = tid >> 2, s_ko = (tid & 3) * 8;

  f32x4 acc[4][4] = {};

  for (int k0 = 0; k0 < K; k0 += 32) {
#pragma unroll
    for (int i = 0; i < 2; ++i) {
      const int row = s_row + i * 64;
      gload16(&A[(size_t)(m0 + row) * K + k0 + s_ko], &AS[row][s_ko]);
      gload16(&W[(size_t)(n0 + row) * K + k0 + s_ko], &BS[row][s_ko]);
    }
    __syncthreads();
    f16x8 af[4], bf[4];
#pragma unroll
    for (int f = 0; f < 4; ++f) {
      af[f] = *(const f16x8*)&AS[wr * 64 + f * 16 + llo][lhi * 8];
      bf[f] = *(const f16x8*)&BS[wc * 64 + f * 16 + llo][lhi * 8];
    }
#pragma unroll
    for (int m = 0; m < 4; ++m)
#pragma unroll
      for (int n = 0; n < 4; ++n)
        acc[m][n] = __builtin_amdgcn_mfma_f32_16x16x32_f16(af[m], bf[n], acc[m][n], 0, 0, 0);
    __syncthreads();
  }

#pragma unroll
  for (int n = 0; n < 4; ++n) {
    const int col = n0 + wc * 64 + n * 16 + llo;
    const float bv = bias[col];
#pragma unroll
    for (int m = 0; m < 4; ++m) {
      const int rbase = m0 + wr * 64 + m * 16 + lhi * 4;
#pragma unroll
      for (int j = 0; j < 4; ++j) {
        float v = fmaxf(acc[m][n][j] + bv, 0.f);
        C[(size_t)(rbase + j) * ldc + col] = (f16)v;
      }
    }
  }
}

// ---------------------------------------------------------------------------
// 1-pass fp16 GEMM, 64x128 dbuf (PROVEN r10-r16): FF2 (SPLITK) / final.
// ---------------------------------------------------------------------------
template<bool CONCAT>
__global__ __launch_bounds__(256)
void gemm_f16_1p(const f16* __restrict__ A, const f16* __restrict__ A2,
                 const f16* __restrict__ W,
                 float* __restrict__ Cf, float* __restrict__ Cf1,
                 int ldc, int K)
{
  __shared__ f16 AS[2][64][32], BS[2][128][32];
  const int tid = threadIdx.x;
  const int lane = tid & 63, w = tid >> 6;
  const int wr = w >> 1, wc = w & 1;
  const int lhi = lane >> 4, llo = lane & 15;
  const int n0 = blockIdx.x * 128;
  const int m0 = blockIdx.y * 64;
  const int half = K >> 1;
  const int kbeg = blockIdx.z * half;
  const int nt = half / 32;
  if (blockIdx.z == 1) Cf = Cf1;

  const int s_row = tid >> 2, s_ko = (tid & 3) * 8;

  auto stage = [&](int k0, int buf) {
    const int gk = k0 + s_ko;
    const f16* s = A;
    size_t g;
    if (CONCAT) {
      if (gk < Ee) { g = (size_t)(m0 + s_row) * Ee + gk; }
      else { g = (size_t)(m0 + s_row) * Ee + (gk - Ee); s = A2; }
    } else {
      g = (size_t)(m0 + s_row) * K + gk;
    }
    gload16(&s[g], &AS[buf][s_row][s_ko]);
#pragma unroll
    for (int i = 0; i < 2; ++i)
      gload16(&W[(size_t)(n0 + s_row + i * 64) * K + gk], &BS[buf][s_row + i * 64][s_ko]);
  };

  f32x4 acc[2][4] = {};
  stage(kbeg, 0);
  __syncthreads();
  int cur = 0;
  for (int t = 0; t < nt; ++t) {
    if (t + 1 < nt) stage(kbeg + (t + 1) * 32, cur ^ 1);
    f16x8 af[2], bf[4];
#pragma unroll
    for (int m = 0; m < 2; ++m)
      af[m] = *(const f16x8*)&AS[cur][wr * 32 + m * 16 + llo][lhi * 8];
#pragma unroll
    for (int n = 0; n < 4; ++n)
      bf[n] = *(const f16x8*)&BS[cur][wc * 64 + n * 16 + llo][lhi * 8];
#pragma unroll
    for (int m = 0; m < 2; ++m)
#pragma unroll
      for (int n = 0; n < 4; ++n)
        acc[m][n] = __builtin_amdgcn_mfma_f32_16x16x32_f16(af[m], bf[n], acc[m][n], 0, 0, 0);
    __syncthreads();
    cur ^= 1;
  }

#pragma unroll
  for (int n = 0; n < 4; ++n) {
    const int col = n0 + wc * 64 + n * 16 + llo;
#pragma unroll
    for (int m = 0; m < 2; ++m) {
      const int rbase = m0 + wr * 32 + m * 16 + lhi * 4;
#pragma unroll
      for (int j = 0; j < 4; ++j)
        Cf[(size_t)(rbase + j) * ldc + col] = acc[m][n][j];
    }
  }
}

// ---------------------------------------------------------------------------
// QKV projection (PROVEN r11-r16): 64x128 dbuf, grid.x=24, sec = bx>>3.
// Q,K: 3-pass f16 (h,l) -> split (h,l) out. V: 1-pass -> plain f16 out.
// ---------------------------------------------------------------------------
__global__ __launch_bounds__(256)
void gemm_qkv(const f16* __restrict__ Ah_g, const f16* __restrict__ Al_g,
              const f16* __restrict__ Wh, const f16* __restrict__ Wl,
              f16* __restrict__ Qh, f16* __restrict__ Ql,
              f16* __restrict__ Kh, f16* __restrict__ Kl,
              f16* __restrict__ Vv)
{
  __shared__ f16 AhS[2][64][32], AlS[2][64][32];
  __shared__ f16 BhS[2][128][32], BlS[2][128][32];
  const int tid = threadIdx.x;
  const int lane = tid & 63, w = tid >> 6;
  const int wr = w >> 1, wc = w & 1;
  const int lhi = lane >> 4, llo = lane & 15;
  const int sec = blockIdx.x >> 3;
  const bool three = (sec < 2);
  const int n0 = (blockIdx.x & 7) * 128;
  Wh += (size_t)sec << 20;
  Wl += (size_t)sec << 20;
  const int m0 = blockIdx.y * 64;
  const int s_row = tid >> 2, s_ko = (tid & 3) * 8;

  auto stage = [&](int k0, int buf) {
    const size_t g = (size_t)(m0 + s_row) * Ee + k0 + s_ko;
    gload16(&Ah_g[g], &AhS[buf][s_row][s_ko]);
    if (three) gload16(&Al_g[g], &AlS[buf][s_row][s_ko]);
#pragma unroll
    for (int i = 0; i < 2; ++i) {
      size_t gb = (size_t)(n0 + s_row + i * 64) * Ee + k0 + s_ko;
      gload16(&Wh[gb], &BhS[buf][s_row + i * 64][s_ko]);
      if (three) gload16(&Wl[gb], &BlS[buf][s_row + i * 64][s_ko]);
    }
  };

  f32x4 acc[2][4] = {};
  stage(0, 0);
  __syncthreads();
  int cur = 0;
  for (int t = 0; t < Ee / 32; ++t) {
    if (t + 1 < Ee / 32) stage((t + 1) * 32, cur ^ 1);
    f16x8 ah[2], bh[4];
#pragma unroll
    for (int m = 0; m < 2; ++m)
      ah[m] = *(const f16x8*)&AhS[cur][wr * 32 + m * 16 + llo][lhi * 8];
#pragma unroll
    for (int n = 0; n < 4; ++n)
      bh[n] = *(const f16x8*)&BhS[cur][wc * 64 + n * 16 + llo][lhi * 8];
    if (three) {
      f16x8 al[2], bl[4];
#pragma unroll
      for (int m = 0; m < 2; ++m)
        al[m] = *(const f16x8*)&AlS[cur][wr * 32 + m * 16 + llo][lhi * 8];
#pragma unroll
      for (int n = 0; n < 4; ++n)
        bl[n] = *(const f16x8*)&BlS[cur][wc * 64 + n * 16 + llo][lhi * 8];
#pragma unroll
      for (int m = 0; m < 2; ++m)
#pragma unroll
        for (int n = 0; n < 4; ++n) {
          acc[m][n] = __builtin_amdgcn_mfma_f32_16x16x32_f16(ah[m], bh[n], acc[m][n], 0, 0, 0);
          acc[m][n] = __builtin_amdgcn_mfma_f32_16x16x32_f16(ah[m], bl[n], acc[m][n], 0, 0, 0);
          acc[m][n] = __builtin_amdgcn_mfma_f32_16x16x32_f16(al[m], bh[n], acc[m][n], 0, 0, 0);
        }
    } else {
#pragma unroll
      for (int m = 0; m < 2; ++m)
#pragma unroll
        for (int n = 0; n < 4; ++n)
          acc[m][n] = __builtin_amdgcn_mfma_f32_16x16x32_f16(ah[m], bh[n], acc[m][n], 0, 0, 0);
    }
    __syncthreads();
    cur ^= 1;
  }

#pragma unroll
  for (int n = 0; n < 4; ++n) {
    const int col = n0 + wc * 64 + n * 16 + llo;
#pragma unroll
    for (int m = 0; m < 2; ++m) {
      const int rbase = m0 + wr * 32 + m * 16 + lhi * 4;
#pragma unroll
      for (int j = 0; j < 4; ++j) {
        const float v = acc[m][n][j];
        const size_t idx = (size_t)(rbase + j) * Ee + col;
        if (sec == 0) {
          f16 h = (f16)v;
          Qh[idx] = h;
          Ql[idx] = (f16)(v - (float)h);
        } else if (sec == 1) {
          f16 h = (f16)v;
          Kh[idx] = h;
          Kl[idx] = (f16)(v - (float)h);
        } else {
          Vv[idx] = (f16)v;
        }
      }
    }
  }
}

// ---------------------------------------------------------------------------
// Split-f16 MFMA flash attention (PROVEN r11-r16, byte-identical), causal.
// ---------------------------------------------------------------------------
__global__ __launch_bounds__(256)
void attn_ms(const f16* __restrict__ Qh_g, const f16* __restrict__ Ql_g,
             const f16* __restrict__ Kh_g, const f16* __restrict__ Kl_g,
             const f16* __restrict__ Vv_g, float* __restrict__ O)
{
  __shared__ f16 Ksh[64][72], Ksl[64][72];   // [s][d]
  __shared__ f16 Vs[64][72];                 // [d][s] (transposed)
  __shared__ f16 Pw[4][16][72];              // per-wave P [q_local][s]
  const int tid = threadIdx.x;
  const int lane = tid & 63, w = tid >> 6;
  const int lhi = lane >> 4, llo = lane & 15;
  const int q0 = blockIdx.x * 64;
  const int bh = blockIdx.y;
  const size_t base = (size_t)(bh >> 4) * Tt * Ee + (size_t)(bh & 15) * Dd;

  f16x8 qfh[2], qfl[2];
#pragma unroll
  for (int ks = 0; ks < 2; ++ks) {
    const size_t qoff = base + (size_t)(q0 + w * 16 + llo) * Ee + ks * 32 + lhi * 8;
    qfh[ks] = *(const f16x8*)&Qh_g[qoff];
    qfl[ks] = *(const f16x8*)&Ql_g[qoff];
  }

  f32x4 oacc[4] = {};
  float m_run[4], l_run[4];
#pragma unroll
  for (int j = 0; j < 4; ++j) { m_run[j] = -INFINITY; l_run[j] = 0.f; }

  for (int s0 = 0; s0 <= q0; s0 += 64) {
#pragma unroll
    for (int pass = 0; pass < 2; ++pass) {
      int c = tid + 256 * pass;
      int row = c >> 3, d0 = (c & 7) * 8;
      const size_t g = base + (size_t)(s0 + row) * Ee + d0;
      f16x8 kh = *(const f16x8*)&Kh_g[g];
      f16x8 kl = *(const f16x8*)&Kl_g[g];
      f16x8 vf = *(const f16x8*)&Vv_g[g];
      *(f16x8*)&Ksh[row][d0] = kh;
      *(f16x8*)&Ksl[row][d0] = kl;
#pragma unroll
      for (int j = 0; j < 8; ++j) Vs[d0 + j][row] = vf[j];
    }
    __syncthreads();

    f32x4 sacc[4] = {};
#pragma unroll
    for (int ks = 0; ks < 2; ++ks)
#pragma unroll
      for (int n = 0; n < 4; ++n) {
        f16x8 kfh = *(const f16x8*)&Ksh[n * 16 + llo][ks * 32 + lhi * 8];
        f16x8 kfl = *(const f16x8*)&Ksl[n * 16 + llo][ks * 32 + lhi * 8];
        sacc[n] = __builtin_amdgcn_mfma_f32_16x16x32_f16(qfh[ks], kfh, sacc[n], 0, 0, 0);
        sacc[n] = __builtin_amdgcn_mfma_f32_16x16x32_f16(qfh[ks], kfl, sacc[n], 0, 0, 0);
        sacc[n] = __builtin_amdgcn_mfma_f32_16x16x32_f16(qfl[ks], kfh, sacc[n], 0, 0, 0);
      }

    if (s0 == q0) {
#pragma unroll
      for (int n = 0; n < 4; ++n)
#pragma unroll
        for (int j = 0; j < 4; ++j)
          if (n * 16 + llo > w * 16 + lhi * 4 + j) sacc[n][j] = -INFINITY;
    }

    float scj[4];
#pragma unroll
    for (int j = 0; j < 4; ++j) {
      float mt = fmaxf(fmaxf(sacc[0][j], sacc[1][j]), fmaxf(sacc[2][j], sacc[3][j]));
#pragma unroll
      for (int off = 1; off < 16; off <<= 1) mt = fmaxf(mt, __shfl_xor(mt, off));
      float mn = fmaxf(m_run[j], mt);
      scj[j] = __expf(m_run[j] - mn);
      m_run[j] = mn;
      float rs = 0.f;
#pragma unroll
      for (int n = 0; n < 4; ++n) {
        float pp = __expf(sacc[n][j] - mn);
        sacc[n][j] = pp;
        rs += pp;
      }
#pragma unroll
      for (int off = 1; off < 16; off <<= 1) rs += __shfl_xor(rs, off);
      l_run[j] = l_run[j] * scj[j] + rs;
    }

#pragma unroll
    for (int n = 0; n < 4; ++n)
#pragma unroll
      for (int j = 0; j < 4; ++j)
        Pw[w][lhi * 4 + j][n * 16 + llo] = (f16)sacc[n][j];
#pragma unroll
    for (int df = 0; df < 4; ++df)
#pragma unroll
      for (int j = 0; j < 4; ++j)
        oacc[df][j] *= scj[j];

#pragma unroll
    for (int ks = 0; ks < 2; ++ks) {
      f16x8 pf = *(const f16x8*)&Pw[w][llo][ks * 32 + lhi * 8];
#pragma unroll
      for (int df = 0; df < 4; ++df) {
        f16x8 vfr = *(const f16x8*)&Vs[df * 16 + llo][ks * 32 + lhi * 8];
        oacc[df] = __builtin_amdgcn_mfma_f32_16x16x32_f16(pf, vfr, oacc[df], 0, 0, 0);
      }
    }
    __syncthreads();
  }

#pragma unroll
  for (int j = 0; j < 4; ++j) {
    float inv = 1.f / l_run[j];
#pragma unroll
    for (int df = 0; df < 4; ++df)
      O[base + (size_t)(q0 + w * 16 + lhi * 4 + j) * Ee + df * 16 + llo] =
          oacc[df][j] * inv;
  }
}

// ---------------------------------------------------------------------------
// Per-head LN over D=64 + residual (PROVEN r11-r16); fp32 + (h,l) f16.
// ---------------------------------------------------------------------------
__global__ __launch_bounds__(256)
void attn_ln_res(const float* __restrict__ O, const float* Yin,
                 const float* __restrict__ g, const float* __restrict__ bta,
                 float* Yout, f16* __restrict__ Yh, f16* __restrict__ Yl)
{
  const int tid = threadIdx.x;
  const int w = (blockIdx.x << 2) + (tid >> 6);
  const int lane = tid & 63;
  const int m = w >> 4;
  const int h = w & 15;
  const size_t idx = (size_t)m * Ee + h * Dd + lane;
  float x = O[idx];
  float s = x, s2 = x * x;
#pragma unroll
  for (int off = 1; off < 64; off <<= 1) {
    s  += __shfl_xor(s, off);
    s2 += __shfl_xor(s2, off);
  }
  float mean = s * (1.f / 64.f);
  float var  = s2 * (1.f / 64.f) - mean * mean;
  float inv  = rsqrtf(var + EPS);
  float r = Yin[idx] + (x - mean) * inv * g[h * Dd + lane] + bta[h * Dd + lane];
  Yout[idx] = r;
  f16 hh = (f16)r;
  Yh[idx] = hh;
  Yl[idx] = (f16)(r - (float)hh);
}

// ---------------------------------------------------------------------------
// Row LN over E=1024 + residual (PROVEN r11-r16). Input = T0 + T1 + bias.
// ---------------------------------------------------------------------------
__global__ __launch_bounds__(256)
void ff_ln_res(const float* __restrict__ T0, const float* __restrict__ T1,
               const float* __restrict__ b2,
               const float* Yin, const float* __restrict__ g,
               const float* __restrict__ bb,
               float* Yout, f16* __restrict__ Yh, f16* __restrict__ Yl)
{
  __shared__ float red[8];
  const int m = blockIdx.x;
  const int tid = threadIdx.x;
  const size_t basep = (size_t)m * Ee;
  float4 xa = *(const float4*)&T0[basep + (tid << 2)];
  float4 xb = *(const float4*)&T1[basep + (tid << 2)];
  float4 bv2 = *(const float4*)&b2[tid << 2];
  float xv[4] = {xa.x + xb.x + bv2.x, xa.y + xb.y + bv2.y,
                 xa.z + xb.z + bv2.z, xa.w + xb.w + bv2.w};
  float s  = xv[0] + xv[1] + xv[2] + xv[3];
  float s2 = xv[0]*xv[0] + xv[1]*xv[1] + xv[2]*xv[2] + xv[3]*xv[3];
#pragma unroll
  for (int off = 1; off < 64; off <<= 1) {
    s  += __shfl_xor(s, off);
    s2 += __shfl_xor(s2, off);
  }
  const int wid = tid >> 6;
  if ((tid & 63) == 0) { red[wid] = s; red[4 + wid] = s2; }
  __syncthreads();
  s  = red[0] + red[1] + red[2] + red[3];
  s2 = red[4] + red[5] + red[6] + red[7];
  float mean = s * (1.f / Ee);
  float var  = s2 * (1.f / Ee) - mean * mean;
  float inv  = rsqrtf(var + EPS);
  float4 y  = *(const float4*)&Yin[basep + (tid << 2)];
  float4 gg = *(const float4*)&g[tid << 2];
  float4 bv = *(const float4*)&bb[tid << 2];
  float gga[4] = {gg.x, gg.y, gg.z, gg.w};
  float bva[4] = {bv.x, bv.y, bv.z, bv.w};
  float ya[4] = {y.x, y.y, y.z, y.w};
  float o[4];
#pragma unroll
  for (int j = 0; j < 4; ++j) {
    o[j] = ya[j] + (xv[j] - mean) * inv * gga[j] + bva[j];
    f16 hh = (f16)o[j];
    Yh[basep + (tid << 2) + j] = hh;
    Yl[basep + (tid << 2) + j] = (f16)(o[j] - (float)hh);
  }
  *(float4*)&Yout[basep + (tid << 2)] = *(float4*)o;
}

// out = p0 + p1 + bias (final linear reduce)
__global__ __launch_bounds__(256)
void add2_bias(const float* __restrict__ p0, const float* __restrict__ p1,
               const float* __restrict__ b, float* __restrict__ out)
{
  const size_t i = ((size_t)blockIdx.x * 256 + threadIdx.x) * 4;
  const int col = (int)(i & (Ee - 1));
  float4 a = *(const float4*)&p0[i];
  float4 c = *(const float4*)&p1[i];
  float4 bb = *(const float4*)&b[col];
  float4 o;
  o.x = a.x + c.x + bb.x; o.y = a.y + c.y + bb.y;
  o.z = a.z + c.z + bb.z; o.w = a.w + c.w + bb.w;
  *(float4*)&out[i] = o;
}

// fp32 -> (hi,lo) f16 split for BOTH branches in one launch (PROVEN r15/r16).
__global__ __launch_bounds__(256)
void split_act2(const float* __restrict__ in,
                f16* __restrict__ oh1, f16* __restrict__ ol1,
                f16* __restrict__ oh2, f16* __restrict__ ol2)
{
  const size_t nb = gridDim.x >> 1;
  size_t bid = blockIdx.x;
  f16 *oh, *ol;
  if (bid < nb) { oh = oh1; ol = ol1; }
  else { bid -= nb; oh = oh2; ol = ol2; }
  const size_t i = (bid * 256 + threadIdx.x) * 4;
  float4 v = *(const float4*)&in[i];
  float f[4] = {v.x, v.y, v.z, v.w};
#pragma unroll
  for (int j = 0; j < 4; ++j) {
    f16 h = (f16)f[j];
    oh[i + j] = h;
    ol[i + j] = (f16)(f[j] - (float)h);
  }
}

// ---------------------------------------------------------------------------
// FAST transpose-convert (PROVEN r16): fp32 [R][C] -> f16 [C][R].
// ---------------------------------------------------------------------------
__device__ __forceinline__ void cvtT_tile(const float* in, f16* outp,
                                          int R, int C, int tx, int ty, int tid)
{
  __shared__ float tile[64][33];
  const int c0 = tx * 32, r0 = ty * 64;
  const int r = tid >> 2, c8 = (tid & 3) * 8;
  const float* src = &in[(size_t)(r0 + r) * C + c0 + c8];
  float4 a = *(const float4*)src;
  float4 b = *(const float4*)(src + 4);
  tile[r][c8 + 0] = a.x; tile[r][c8 + 1] = a.y;
  tile[r][c8 + 2] = a.z; tile[r][c8 + 3] = a.w;
  tile[r][c8 + 4] = b.x; tile[r][c8 + 5] = b.y;
  tile[r][c8 + 6] = b.z; tile[r][c8 + 7] = b.w;
  __syncthreads();
  const int oc = tid >> 3, rr = (tid & 7) * 8;
  f16x8 o;
#pragma unroll
  for (int j = 0; j < 8; ++j) o[j] = (f16)tile[rr + j][oc];
  *(f16x8*)&outp[(size_t)(c0 + oc) * R + r0 + rr] = o;
}

__global__ __launch_bounds__(256)
void cvtT_f16(const float* __restrict__ in, f16* __restrict__ outp, int R, int C)
{
  const int nx = C >> 5;
  cvtT_tile(in, outp, R, C, blockIdx.x % nx, blockIdx.x / nx, threadIdx.x);
}

// Fused FF weight transpose (fast, PROVEN r16).
__global__ __launch_bounds__(256)
void cvtT_ff(const float* __restrict__ w1, const float* __restrict__ w2,
             f16* __restrict__ o1, f16* __restrict__ o2)
{
  constexpr int NT1 = (Ff / 32) * (Ee / 64);   // 2048
  int id = blockIdx.x;
  const float* in; f16* outp; int R, C;
  if (id < NT1) { in = w1; outp = o1; R = Ee; C = Ff; }
  else { id -= NT1; in = w2; outp = o2; R = Ff; C = Ee; }
  const int nx = C >> 5;
  cvtT_tile(in, outp, R, C, id % nx, id / nx, threadIdx.x);
}

// Fast fused QKV weight transpose-split (PROVEN r16).
__global__ __launch_bounds__(256)
void cvtT_qkv(const float* __restrict__ wq, const float* __restrict__ wk,
              const float* __restrict__ wv, f16* __restrict__ out_h,
              f16* __restrict__ out_l)
{
  __shared__ float tile[64][33];
  const int z = blockIdx.z, sec = z >> 4, hh = z & 15;
  const float* in = (sec == 0) ? wq : (sec == 1) ? wk : wv;
  const size_t zi = (size_t)hh * Ee * Dd;
  const size_t zo = ((size_t)sec << 20) + (size_t)hh * Ee * Dd;
  const int c0 = blockIdx.x * 32, r0 = blockIdx.y * 64;
  const int tid = threadIdx.x;
  const int r = tid >> 2, c8 = (tid & 3) * 8;
  const float* src = &in[zi + (size_t)(r0 + r) * Dd + c0 + c8];
  float4 a = *(const float4*)src;
  float4 b = *(const float4*)(src + 4);
  tile[r][c8 + 0] = a.x; tile[r][c8 + 1] = a.y;
  tile[r][c8 + 2] = a.z; tile[r][c8 + 3] = a.w;
  tile[r][c8 + 4] = b.x; tile[r][c8 + 5] = b.y;
  tile[r][c8 + 6] = b.z; tile[r][c8 + 7] = b.w;
  __syncthreads();
  const int oc = tid >> 3, rr = (tid & 7) * 8;
  f16x8 oh, ol;
#pragma unroll
  for (int j = 0; j < 8; ++j) {
    float f = tile[rr + j][oc];
    f16 h = (f16)f;
    oh[j] = h;
    ol[j] = (f16)(f - (float)h);
  }
  const size_t ob = zo + (size_t)(c0 + oc) * Ee + r0 + rr;
  *(f16x8*)&out_h[ob] = oh;
  *(f16x8*)&out_l[ob] = ol;
}

// ---------------------------------------------------------------------------
extern "C" void kernel_launch(void* const* d_in, const int* in_sizes, int n_in,
                              void* d_out, int out_size, void* d_ws, size_t ws_size,
                              hipStream_t stream)
{
  const float* x     = (const float*)d_in[0];
  const float* mh_wq = (const float*)d_in[1];
  const float* mh_wk = (const float*)d_in[2];
  const float* mh_wv = (const float*)d_in[3];
  const float* mh_g  = (const float*)d_in[4];
  const float* mh_b  = (const float*)d_in[5];
  const float* ff_w1 = (const float*)d_in[6];
  const float* ff_b1 = (const float*)d_in[7];
  const float* ff_w2 = (const float*)d_in[8];
  const float* ff_b2 = (const float*)d_in[9];
  const float* ff_g  = (const float*)d_in[10];
  const float* ff_bb = (const float*)d_in[11];
  const float* lt_w  = (const float*)d_in[12];
  const float* lt_b  = (const float*)d_in[13];
  float* out = (float*)d_out;

  // ===== EXACT r11/r15/r16 buffer layout (proven). 88 MB. =====
  const size_t ME = (size_t)Mm * Ee;   // 2M elements
  char* p = (char*)d_ws;
  auto alloc = [&](size_t bytes) { void* r = (void*)p; p += (bytes + 255) & ~(size_t)255; return r; };
  float* bufA  = (float*)alloc(ME * 4);                // 8 MB
  f16*   bufAh = (f16*)alloc(ME * 2);                  // 4 MB
  f16*   bufAl = (f16*)alloc(ME * 2);                  // 4 MB
  float* bufB  = (float*)alloc(ME * 4);                // 8 MB
  f16*   bufBh = (f16*)alloc(ME * 2);                  // 4 MB
  f16*   bufBl = (f16*)alloc(ME * 2);                  // 4 MB
  f16*   wt_h  = (f16*)alloc((size_t)Ff * Ee * 2);     // 8 MB (w1 / qkv-h / lt)
  f16*   wt_l  = (f16*)alloc((size_t)Ff * Ee * 2);     // 8 MB (w2 / qkv-l)
  float* reg   = (float*)alloc((size_t)10 * 1024 * 1024 * 4);  // 40 MB union
  f16*   qh_   = (f16*)reg;
  f16*   ql_   = qh_ + ME;
  f16*   kh_   = qh_ + 2 * ME;
  f16*   kl_   = qh_ + 3 * ME;
  f16*   vv_   = qh_ + 4 * ME;
  float* ob    = reg + 5 * 1024 * 1024;        // attn out (20..28 MB)
  f16*   hid   = (f16*)reg;                    // ff phase: [M,F] f16 = 16 MB
  float* tmp   = reg + 8 * 1024 * 1024;        // fp32 partial (32..40 MB)

  // mh: byte-identical dataflow to r16.
  auto mh = [&](int i, const float* srcF, const f16* srcH, const f16* srcL,
                float* dstF, f16* dstH, f16* dstL) {
    const size_t wo = (size_t)i * Hh * Ee * Dd;
    cvtT_qkv<<<dim3(Dd / 32, Ee / 64, 48), 256, 0, stream>>>(
        mh_wq + wo, mh_wk + wo, mh_wv + wo, wt_h, wt_l);
    gemm_qkv<<<dim3(24, Mm / 64), 256, 0, stream>>>(
        srcH, srcL, wt_h, wt_l, qh_, ql_, kh_, kl_, vv_);
    attn_ms<<<dim3(Tt / 64, Bb * Hh), 256, 0, stream>>>(qh_, ql_, kh_, kl_, vv_, ob);
    attn_ln_res<<<dim3(Mm * Hh / 4), 256, 0, stream>>>(
        ob, srcF, mh_g + (size_t)i * Hh * Dd, mh_b + (size_t)i * Hh * Dd, dstF, dstH, dstL);
  };
  // ff: byte-identical dataflow to r16.
  auto ff = [&](int i, const float* srcF, const f16* srcH,
                float* dstF, f16* dstH, f16* dstL, float* tmp1) {
    cvtT_ff<<<dim3((Ff / 32) * (Ee / 64) + (Ee / 32) * (Ff / 64)), 256, 0, stream>>>(
        ff_w1 + (size_t)i * Ee * Ff, ff_w2 + (size_t)i * Ff * Ee, wt_h, wt_l);
    gemm_f16_128<<<dim3(Ff / 128, Mm / 128), 256, 0, stream>>>(
        srcH, wt_h, ff_b1 + (size_t)i * Ff, hid, Ff, Ee);
    gemm_f16_1p<false><<<dim3(Ee / 128, Mm / 64, 2), 256, 0, stream>>>(
        hid, nullptr, wt_l, tmp, tmp1, Ee, Ff);
    ff_ln_res<<<dim3(Mm), 256, 0, stream>>>(
        tmp, tmp1, ff_b2 + (size_t)i * Ee,
        srcF, ff_g + (size_t)i * Ee, ff_bb + (size_t)i * Ee, dstF, dstH, dstL);
  };

  // both branches' x-split in one launch
  split_act2<<<dim3(2 * ME / 1024), 256, 0, stream>>>(x, bufAh, bufAl, bufBh, bufBl);

  // out_one branch: ff(3, mh(4, mh(0, x)))   [bufB fp32 dead -> tmp1]
  mh(0, x, bufAh, bufAl, bufA, bufAh, bufAl);
  mh(4, bufA, bufAh, bufAl, bufA, bufAh, bufAl);
  ff(3, bufA, bufAh, bufA, bufAh, bufAl, bufB);

  // out_two branch: 3 encoder blocks then decoder  [bufA fp32 dead -> tmp1]
  mh(1, x, bufBh, bufBl, bufB, bufBh, bufBl);
  ff(0, bufB, bufBh, bufB, bufBh, bufBl, bufA);
  mh(2, bufB, bufBh, bufBl, bufB, bufBh, bufBl);
  ff(1, bufB, bufBh, bufB, bufBh, bufBl, bufA);
  mh(3, bufB, bufBh, bufBl, bufB, bufBh, bufBl);
  ff(2, bufB, bufBh, bufB, bufBh, bufBl, bufA);
  mh(4, bufB, bufBh, bufBl, bufB, bufBh, bufBl);
  ff(3, bufB, bufBh, bufB, bufBh, bufBl, bufA);

  // final: out = concat(A,B)@lt_w + lt_b, 1-pass f16, split-K=2 into dead bufs
  cvtT_f16<<<dim3((Ee / 32) * (2 * Ee / 64)), 256, 0, stream>>>(lt_w, wt_h, 2 * Ee, Ee);
  gemm_f16_1p<true><<<dim3(Ee / 128, Mm / 64, 2), 256, 0, stream>>>(
      bufAh, bufBh, wt_h, bufA, bufB, Ee, 2 * Ee);
  add2_bias<<<dim3(ME / 1024), 256, 0, stream>>>(bufA, bufB, lt_b, out);
}

// Round 19
// 977.881 us; speedup vs baseline: 1.1778x; 1.0272x over previous
//
#include <hip/hip_runtime.h>
#include <math.h>

#define Bb 4
#define Tt 512
#define Ee 1024
#define Hh 16
#define Dd 64
#define Ff 4096
#define Mm (Bb*Tt)   // 2048
static constexpr float EPS = 1e-5f;

typedef __attribute__((ext_vector_type(4))) float f32x4;
typedef _Float16 f16;
typedef __attribute__((ext_vector_type(8))) _Float16 f16x8;

// async global->LDS, 16B per lane. LDS dest must be lane-linear.
__device__ __forceinline__ void gload16(const void* g, void* l) {
  __builtin_amdgcn_global_load_lds(
      (const __attribute__((address_space(1))) unsigned int*)g,
      (__attribute__((address_space(3))) unsigned int*)l, 16, 0, 0);
}

// ---------------------------------------------------------------------------
// FF1: 1-pass fp16 GEMM, m97 structure (PROVEN r10-r18). 128x128, BK=32,
// single-buffer 16KB LDS, gload_lds staging. Bias+ReLU, f16 out.
// ---------------------------------------------------------------------------
__global__ __launch_bounds__(256)
void gemm_f16_128(const f16* __restrict__ A, const f16* __restrict__ W,
                  const float* __restrict__ bias,
                  f16* __restrict__ C, int ldc, int K)
{
  __shared__ f16 AS[128][32], BS[128][32];
  const int tid = threadIdx.x;
  const int lane = tid & 63, w = tid >> 6;
  const int wr = w >> 1, wc = w & 1;
  const int lhi = lane >> 4, llo = lane & 15;
  const int n0 = blockIdx.x * 128, m0 = blockIdx.y * 128;
  const int s_row = tid >> 2, s_ko = (tid & 3) * 8;

  f32x4 acc[4][4] = {};

  for (int k0 = 0; k0 < K; k0 += 32) {
#pragma unroll
    for (int i = 0; i < 2; ++i) {
      const int row = s_row + i * 64;
      gload16(&A[(size_t)(m0 + row) * K + k0 + s_ko], &AS[row][s_ko]);
      gload16(&W[(size_t)(n0 + row) * K + k0 + s_ko], &BS[row][s_ko]);
    }
    __syncthreads();
    f16x8 af[4], bf[4];
#pragma unroll
    for (int f = 0; f < 4; ++f) {
      af[f] = *(const f16x8*)&AS[wr * 64 + f * 16 + llo][lhi * 8];
      bf[f] = *(const f16x8*)&BS[wc * 64 + f * 16 + llo][lhi * 8];
    }
#pragma unroll
    for (int m = 0; m < 4; ++m)
#pragma unroll
      for (int n = 0; n < 4; ++n)
        acc[m][n] = __builtin_amdgcn_mfma_f32_16x16x32_f16(af[m], bf[n], acc[m][n], 0, 0, 0);
    __syncthreads();
  }

#pragma unroll
  for (int n = 0; n < 4; ++n) {
    const int col = n0 + wc * 64 + n * 16 + llo;
    const float bv = bias[col];
#pragma unroll
    for (int m = 0; m < 4; ++m) {
      const int rbase = m0 + wr * 64 + m * 16 + lhi * 4;
#pragma unroll
      for (int j = 0; j < 4; ++j) {
        float v = fmaxf(acc[m][n][j] + bv, 0.f);
        C[(size_t)(rbase + j) * ldc + col] = (f16)v;
      }
    }
  }
}

// ---------------------------------------------------------------------------
// 1-pass fp16 GEMM, 64x128 dbuf (PROVEN r10-r18): FF2 (SPLITK) / final.
// ---------------------------------------------------------------------------
template<bool CONCAT>
__global__ __launch_bounds__(256)
void gemm_f16_1p(const f16* __restrict__ A, const f16* __restrict__ A2,
                 const f16* __restrict__ W,
                 float* __restrict__ Cf, float* __restrict__ Cf1,
                 int ldc, int K)
{
  __shared__ f16 AS[2][64][32], BS[2][128][32];
  const int tid = threadIdx.x;
  const int lane = tid & 63, w = tid >> 6;
  const int wr = w >> 1, wc = w & 1;
  const int lhi = lane >> 4, llo = lane & 15;
  const int n0 = blockIdx.x * 128;
  const int m0 = blockIdx.y * 64;
  const int half = K >> 1;
  const int kbeg = blockIdx.z * half;
  const int nt = half / 32;
  if (blockIdx.z == 1) Cf = Cf1;

  const int s_row = tid >> 2, s_ko = (tid & 3) * 8;

  auto stage = [&](int k0, int buf) {
    const int gk = k0 + s_ko;
    const f16* s = A;
    size_t g;
    if (CONCAT) {
      if (gk < Ee) { g = (size_t)(m0 + s_row) * Ee + gk; }
      else { g = (size_t)(m0 + s_row) * Ee + (gk - Ee); s = A2; }
    } else {
      g = (size_t)(m0 + s_row) * K + gk;
    }
    gload16(&s[g], &AS[buf][s_row][s_ko]);
#pragma unroll
    for (int i = 0; i < 2; ++i)
      gload16(&W[(size_t)(n0 + s_row + i * 64) * K + gk], &BS[buf][s_row + i * 64][s_ko]);
  };

  f32x4 acc[2][4] = {};
  stage(kbeg, 0);
  __syncthreads();
  int cur = 0;
  for (int t = 0; t < nt; ++t) {
    if (t + 1 < nt) stage(kbeg + (t + 1) * 32, cur ^ 1);
    f16x8 af[2], bf[4];
#pragma unroll
    for (int m = 0; m < 2; ++m)
      af[m] = *(const f16x8*)&AS[cur][wr * 32 + m * 16 + llo][lhi * 8];
#pragma unroll
    for (int n = 0; n < 4; ++n)
      bf[n] = *(const f16x8*)&BS[cur][wc * 64 + n * 16 + llo][lhi * 8];
#pragma unroll
    for (int m = 0; m < 2; ++m)
#pragma unroll
      for (int n = 0; n < 4; ++n)
        acc[m][n] = __builtin_amdgcn_mfma_f32_16x16x32_f16(af[m], bf[n], acc[m][n], 0, 0, 0);
    __syncthreads();
    cur ^= 1;
  }

#pragma unroll
  for (int n = 0; n < 4; ++n) {
    const int col = n0 + wc * 64 + n * 16 + llo;
#pragma unroll
    for (int m = 0; m < 2; ++m) {
      const int rbase = m0 + wr * 32 + m * 16 + lhi * 4;
#pragma unroll
      for (int j = 0; j < 4; ++j)
        Cf[(size_t)(rbase + j) * ldc + col] = acc[m][n][j];
    }
  }
}

// ---------------------------------------------------------------------------
// QKV projection (PROVEN r11-r18): 64x128 dbuf, grid.x=24, sec = bx>>3.
// Q,K: 3-pass f16 (h,l) -> split (h,l) out. V: 1-pass -> plain f16 out.
// ---------------------------------------------------------------------------
__global__ __launch_bounds__(256)
void gemm_qkv(const f16* __restrict__ Ah_g, const f16* __restrict__ Al_g,
              const f16* __restrict__ Wh, const f16* __restrict__ Wl,
              f16* __restrict__ Qh, f16* __restrict__ Ql,
              f16* __restrict__ Kh, f16* __restrict__ Kl,
              f16* __restrict__ Vv)
{
  __shared__ f16 AhS[2][64][32], AlS[2][64][32];
  __shared__ f16 BhS[2][128][32], BlS[2][128][32];
  const int tid = threadIdx.x;
  const int lane = tid & 63, w = tid >> 6;
  const int wr = w >> 1, wc = w & 1;
  const int lhi = lane >> 4, llo = lane & 15;
  const int sec = blockIdx.x >> 3;
  const bool three = (sec < 2);
  const int n0 = (blockIdx.x & 7) * 128;
  Wh += (size_t)sec << 20;
  Wl += (size_t)sec << 20;
  const int m0 = blockIdx.y * 64;
  const int s_row = tid >> 2, s_ko = (tid & 3) * 8;

  auto stage = [&](int k0, int buf) {
    const size_t g = (size_t)(m0 + s_row) * Ee + k0 + s_ko;
    gload16(&Ah_g[g], &AhS[buf][s_row][s_ko]);
    if (three) gload16(&Al_g[g], &AlS[buf][s_row][s_ko]);
#pragma unroll
    for (int i = 0; i < 2; ++i) {
      size_t gb = (size_t)(n0 + s_row + i * 64) * Ee + k0 + s_ko;
      gload16(&Wh[gb], &BhS[buf][s_row + i * 64][s_ko]);
      if (three) gload16(&Wl[gb], &BlS[buf][s_row + i * 64][s_ko]);
    }
  };

  f32x4 acc[2][4] = {};
  stage(0, 0);
  __syncthreads();
  int cur = 0;
  for (int t = 0; t < Ee / 32; ++t) {
    if (t + 1 < Ee / 32) stage((t + 1) * 32, cur ^ 1);
    f16x8 ah[2], bh[4];
#pragma unroll
    for (int m = 0; m < 2; ++m)
      ah[m] = *(const f16x8*)&AhS[cur][wr * 32 + m * 16 + llo][lhi * 8];
#pragma unroll
    for (int n = 0; n < 4; ++n)
      bh[n] = *(const f16x8*)&BhS[cur][wc * 64 + n * 16 + llo][lhi * 8];
    if (three) {
      f16x8 al[2], bl[4];
#pragma unroll
      for (int m = 0; m < 2; ++m)
        al[m] = *(const f16x8*)&AlS[cur][wr * 32 + m * 16 + llo][lhi * 8];
#pragma unroll
      for (int n = 0; n < 4; ++n)
        bl[n] = *(const f16x8*)&BlS[cur][wc * 64 + n * 16 + llo][lhi * 8];
#pragma unroll
      for (int m = 0; m < 2; ++m)
#pragma unroll
        for (int n = 0; n < 4; ++n) {
          acc[m][n] = __builtin_amdgcn_mfma_f32_16x16x32_f16(ah[m], bh[n], acc[m][n], 0, 0, 0);
          acc[m][n] = __builtin_amdgcn_mfma_f32_16x16x32_f16(ah[m], bl[n], acc[m][n], 0, 0, 0);
          acc[m][n] = __builtin_amdgcn_mfma_f32_16x16x32_f16(al[m], bh[n], acc[m][n], 0, 0, 0);
        }
    } else {
#pragma unroll
      for (int m = 0; m < 2; ++m)
#pragma unroll
        for (int n = 0; n < 4; ++n)
          acc[m][n] = __builtin_amdgcn_mfma_f32_16x16x32_f16(ah[m], bh[n], acc[m][n], 0, 0, 0);
    }
    __syncthreads();
    cur ^= 1;
  }

#pragma unroll
  for (int n = 0; n < 4; ++n) {
    const int col = n0 + wc * 64 + n * 16 + llo;
#pragma unroll
    for (int m = 0; m < 2; ++m) {
      const int rbase = m0 + wr * 32 + m * 16 + lhi * 4;
#pragma unroll
      for (int j = 0; j < 4; ++j) {
        const float v = acc[m][n][j];
        const size_t idx = (size_t)(rbase + j) * Ee + col;
        if (sec == 0) {
          f16 h = (f16)v;
          Qh[idx] = h;
          Ql[idx] = (f16)(v - (float)h);
        } else if (sec == 1) {
          f16 h = (f16)v;
          Kh[idx] = h;
          Kl[idx] = (f16)(v - (float)h);
        } else {
          Vv[idx] = (f16)v;
        }
      }
    }
  }
}

// ---------------------------------------------------------------------------
// Split-f16 MFMA flash attention, causal, no 1/sqrt(d) (r11-r18 math).
// NEW (r19): QBLK=128 — 8 waves / 512 threads per block; each K/V tile is
// staged ONCE for 128 q-rows (staging volume 36 -> 20 tiles per (b,h)).
// One 512-thread pass stages a full 64x64 tile (f16x8 per thread per array).
// Causal mask: wave-uniform guard (over-applying elementwise test is safe).
// Per-row math/order identical to r18 -> same numerics.
// ---------------------------------------------------------------------------
__global__ __launch_bounds__(512)
void attn_ms(const f16* __restrict__ Qh_g, const f16* __restrict__ Ql_g,
             const f16* __restrict__ Kh_g, const f16* __restrict__ Kl_g,
             const f16* __restrict__ Vv_g, float* __restrict__ O)
{
  __shared__ f16 Ksh[64][72], Ksl[64][72];   // [s][d]
  __shared__ f16 Vs[64][72];                 // [d][s] (transposed)
  __shared__ f16 Pw[8][16][72];              // per-wave P [q_local][s]
  const int tid = threadIdx.x;
  const int lane = tid & 63, w = tid >> 6;   // w in 0..7
  const int lhi = lane >> 4, llo = lane & 15;
  const int q0 = blockIdx.x * 128;
  const int bh = blockIdx.y;
  const size_t base = (size_t)(bh >> 4) * Tt * Ee + (size_t)(bh & 15) * Dd;

  f16x8 qfh[2], qfl[2];
#pragma unroll
  for (int ks = 0; ks < 2; ++ks) {
    const size_t qoff = base + (size_t)(q0 + w * 16 + llo) * Ee + ks * 32 + lhi * 8;
    qfh[ks] = *(const f16x8*)&Qh_g[qoff];
    qfl[ks] = *(const f16x8*)&Ql_g[qoff];
  }

  f32x4 oacc[4] = {};
  float m_run[4], l_run[4];
#pragma unroll
  for (int j = 0; j < 4; ++j) { m_run[j] = -INFINITY; l_run[j] = 0.f; }

  const int s_end = q0 + 64;   // last tile start needed by rows q0..q0+127
  for (int s0 = 0; s0 <= s_end; s0 += 64) {
    // stage K(h,l) row-major + V transposed: 512 threads cover 64x64 in 1 pass
    {
      const int row = tid >> 3, d0 = (tid & 7) * 8;
      const size_t g = base + (size_t)(s0 + row) * Ee + d0;
      f16x8 kh = *(const f16x8*)&Kh_g[g];
      f16x8 kl = *(const f16x8*)&Kl_g[g];
      f16x8 vf = *(const f16x8*)&Vv_g[g];
      *(f16x8*)&Ksh[row][d0] = kh;
      *(f16x8*)&Ksl[row][d0] = kl;
#pragma unroll
      for (int j = 0; j < 8; ++j) Vs[d0 + j][row] = vf[j];
    }
    __syncthreads();

    // S = Q K^T (3-pass split)
    f32x4 sacc[4] = {};
#pragma unroll
    for (int ks = 0; ks < 2; ++ks)
#pragma unroll
      for (int n = 0; n < 4; ++n) {
        f16x8 kfh = *(const f16x8*)&Ksh[n * 16 + llo][ks * 32 + lhi * 8];
        f16x8 kfl = *(const f16x8*)&Ksl[n * 16 + llo][ks * 32 + lhi * 8];
        sacc[n] = __builtin_amdgcn_mfma_f32_16x16x32_f16(qfh[ks], kfh, sacc[n], 0, 0, 0);
        sacc[n] = __builtin_amdgcn_mfma_f32_16x16x32_f16(qfh[ks], kfl, sacc[n], 0, 0, 0);
        sacc[n] = __builtin_amdgcn_mfma_f32_16x16x32_f16(qfl[ks], kfh, sacc[n], 0, 0, 0);
      }

    // causal mask: this wave's rows are q0+w*16 .. q0+w*16+15.
    // Tile can clip iff s0+63 >= q0+w*16; elementwise test is exact.
    if (s0 + 64 > q0 + w * 16) {
#pragma unroll
      for (int n = 0; n < 4; ++n)
#pragma unroll
        for (int j = 0; j < 4; ++j)
          if (s0 + n * 16 + llo > q0 + w * 16 + lhi * 4 + j) sacc[n][j] = -INFINITY;
    }

    float scj[4];
#pragma unroll
    for (int j = 0; j < 4; ++j) {
      float mt = fmaxf(fmaxf(sacc[0][j], sacc[1][j]), fmaxf(sacc[2][j], sacc[3][j]));
#pragma unroll
      for (int off = 1; off < 16; off <<= 1) mt = fmaxf(mt, __shfl_xor(mt, off));
      float mn = fmaxf(m_run[j], mt);
      scj[j] = __expf(m_run[j] - mn);
      m_run[j] = mn;
      float rs = 0.f;
#pragma unroll
      for (int n = 0; n < 4; ++n) {
        float pp = __expf(sacc[n][j] - mn);
        sacc[n][j] = pp;
        rs += pp;
      }
#pragma unroll
      for (int off = 1; off < 16; off <<= 1) rs += __shfl_xor(rs, off);
      l_run[j] = l_run[j] * scj[j] + rs;
    }

#pragma unroll
    for (int n = 0; n < 4; ++n)
#pragma unroll
      for (int j = 0; j < 4; ++j)
        Pw[w][lhi * 4 + j][n * 16 + llo] = (f16)sacc[n][j];
#pragma unroll
    for (int df = 0; df < 4; ++df)
#pragma unroll
      for (int j = 0; j < 4; ++j)
        oacc[df][j] *= scj[j];

#pragma unroll
    for (int ks = 0; ks < 2; ++ks) {
      f16x8 pf = *(const f16x8*)&Pw[w][llo][ks * 32 + lhi * 8];
#pragma unroll
      for (int df = 0; df < 4; ++df) {
        f16x8 vfr = *(const f16x8*)&Vs[df * 16 + llo][ks * 32 + lhi * 8];
        oacc[df] = __builtin_amdgcn_mfma_f32_16x16x32_f16(pf, vfr, oacc[df], 0, 0, 0);
      }
    }
    __syncthreads();
  }

#pragma unroll
  for (int j = 0; j < 4; ++j) {
    float inv = 1.f / l_run[j];
#pragma unroll
    for (int df = 0; df < 4; ++df)
      O[base + (size_t)(q0 + w * 16 + lhi * 4 + j) * Ee + df * 16 + llo] =
          oacc[df][j] * inv;
  }
}

// ---------------------------------------------------------------------------
// Per-head LN over D=64 + residual (PROVEN r11-r18); fp32 + (h,l) f16.
// ---------------------------------------------------------------------------
__global__ __launch_bounds__(256)
void attn_ln_res(const float* __restrict__ O, const float* Yin,
                 const float* __restrict__ g, const float* __restrict__ bta,
                 float* Yout, f16* __restrict__ Yh, f16* __restrict__ Yl)
{
  const int tid = threadIdx.x;
  const int w = (blockIdx.x << 2) + (tid >> 6);
  const int lane = tid & 63;
  const int m = w >> 4;
  const int h = w & 15;
  const size_t idx = (size_t)m * Ee + h * Dd + lane;
  float x = O[idx];
  float s = x, s2 = x * x;
#pragma unroll
  for (int off = 1; off < 64; off <<= 1) {
    s  += __shfl_xor(s, off);
    s2 += __shfl_xor(s2, off);
  }
  float mean = s * (1.f / 64.f);
  float var  = s2 * (1.f / 64.f) - mean * mean;
  float inv  = rsqrtf(var + EPS);
  float r = Yin[idx] + (x - mean) * inv * g[h * Dd + lane] + bta[h * Dd + lane];
  Yout[idx] = r;
  f16 hh = (f16)r;
  Yh[idx] = hh;
  Yl[idx] = (f16)(r - (float)hh);
}

// ---------------------------------------------------------------------------
// Row LN over E=1024 + residual (PROVEN r11-r18). Input = T0 + T1 + bias.
// ---------------------------------------------------------------------------
__global__ __launch_bounds__(256)
void ff_ln_res(const float* __restrict__ T0, const float* __restrict__ T1,
               const float* __restrict__ b2,
               const float* Yin, const float* __restrict__ g,
               const float* __restrict__ bb,
               float* Yout, f16* __restrict__ Yh, f16* __restrict__ Yl)
{
  __shared__ float red[8];
  const int m = blockIdx.x;
  const int tid = threadIdx.x;
  const size_t basep = (size_t)m * Ee;
  float4 xa = *(const float4*)&T0[basep + (tid << 2)];
  float4 xb = *(const float4*)&T1[basep + (tid << 2)];
  float4 bv2 = *(const float4*)&b2[tid << 2];
  float xv[4] = {xa.x + xb.x + bv2.x, xa.y + xb.y + bv2.y,
                 xa.z + xb.z + bv2.z, xa.w + xb.w + bv2.w};
  float s  = xv[0] + xv[1] + xv[2] + xv[3];
  float s2 = xv[0]*xv[0] + xv[1]*xv[1] + xv[2]*xv[2] + xv[3]*xv[3];
#pragma unroll
  for (int off = 1; off < 64; off <<= 1) {
    s  += __shfl_xor(s, off);
    s2 += __shfl_xor(s2, off);
  }
  const int wid = tid >> 6;
  if ((tid & 63) == 0) { red[wid] = s; red[4 + wid] = s2; }
  __syncthreads();
  s  = red[0] + red[1] + red[2] + red[3];
  s2 = red[4] + red[5] + red[6] + red[7];
  float mean = s * (1.f / Ee);
  float var  = s2 * (1.f / Ee) - mean * mean;
  float inv  = rsqrtf(var + EPS);
  float4 y  = *(const float4*)&Yin[basep + (tid << 2)];
  float4 gg = *(const float4*)&g[tid << 2];
  float4 bv = *(const float4*)&bb[tid << 2];
  float gga[4] = {gg.x, gg.y, gg.z, gg.w};
  float bva[4] = {bv.x, bv.y, bv.z, bv.w};
  float ya[4] = {y.x, y.y, y.z, y.w};
  float o[4];
#pragma unroll
  for (int j = 0; j < 4; ++j) {
    o[j] = ya[j] + (xv[j] - mean) * inv * gga[j] + bva[j];
    f16 hh = (f16)o[j];
    Yh[basep + (tid << 2) + j] = hh;
    Yl[basep + (tid << 2) + j] = (f16)(o[j] - (float)hh);
  }
  *(float4*)&Yout[basep + (tid << 2)] = *(float4*)o;
}

// out = p0 + p1 + bias (final linear reduce)
__global__ __launch_bounds__(256)
void add2_bias(const float* __restrict__ p0, const float* __restrict__ p1,
               const float* __restrict__ b, float* __restrict__ out)
{
  const size_t i = ((size_t)blockIdx.x * 256 + threadIdx.x) * 4;
  const int col = (int)(i & (Ee - 1));
  float4 a = *(const float4*)&p0[i];
  float4 c = *(const float4*)&p1[i];
  float4 bb = *(const float4*)&b[col];
  float4 o;
  o.x = a.x + c.x + bb.x; o.y = a.y + c.y + bb.y;
  o.z = a.z + c.z + bb.z; o.w = a.w + c.w + bb.w;
  *(float4*)&out[i] = o;
}

// fp32 -> (hi,lo) f16 split for BOTH branches in one launch (PROVEN r15-r18).
__global__ __launch_bounds__(256)
void split_act2(const float* __restrict__ in,
                f16* __restrict__ oh1, f16* __restrict__ ol1,
                f16* __restrict__ oh2, f16* __restrict__ ol2)
{
  const size_t nb = gridDim.x >> 1;
  size_t bid = blockIdx.x;
  f16 *oh, *ol;
  if (bid < nb) { oh = oh1; ol = ol1; }
  else { bid -= nb; oh = oh2; ol = ol2; }
  const size_t i = (bid * 256 + threadIdx.x) * 4;
  float4 v = *(const float4*)&in[i];
  float f[4] = {v.x, v.y, v.z, v.w};
#pragma unroll
  for (int j = 0; j < 4; ++j) {
    f16 h = (f16)f[j];
    oh[i + j] = h;
    ol[i + j] = (f16)(f[j] - (float)h);
  }
}

// ---------------------------------------------------------------------------
// FAST transpose-convert (PROVEN r16/r18): fp32 [R][C] -> f16 [C][R].
// ---------------------------------------------------------------------------
__device__ __forceinline__ void cvtT_tile(const float* in, f16* outp,
                                          int R, int C, int tx, int ty, int tid)
{
  __shared__ float tile[64][33];
  const int c0 = tx * 32, r0 = ty * 64;
  const int r = tid >> 2, c8 = (tid & 3) * 8;
  const float* src = &in[(size_t)(r0 + r) * C + c0 + c8];
  float4 a = *(const float4*)src;
  float4 b = *(const float4*)(src + 4);
  tile[r][c8 + 0] = a.x; tile[r][c8 + 1] = a.y;
  tile[r][c8 + 2] = a.z; tile[r][c8 + 3] = a.w;
  tile[r][c8 + 4] = b.x; tile[r][c8 + 5] = b.y;
  tile[r][c8 + 6] = b.z; tile[r][c8 + 7] = b.w;
  __syncthreads();
  const int oc = tid >> 3, rr = (tid & 7) * 8;
  f16x8 o;
#pragma unroll
  for (int j = 0; j < 8; ++j) o[j] = (f16)tile[rr + j][oc];
  *(f16x8*)&outp[(size_t)(c0 + oc) * R + r0 + rr] = o;
}

__global__ __launch_bounds__(256)
void cvtT_f16(const float* __restrict__ in, f16* __restrict__ outp, int R, int C)
{
  const int nx = C >> 5;
  cvtT_tile(in, outp, R, C, blockIdx.x % nx, blockIdx.x / nx, threadIdx.x);
}

// Fused FF weight transpose (fast, PROVEN r16/r18).
__global__ __launch_bounds__(256)
void cvtT_ff(const float* __restrict__ w1, const float* __restrict__ w2,
             f16* __restrict__ o1, f16* __restrict__ o2)
{
  constexpr int NT1 = (Ff / 32) * (Ee / 64);   // 2048
  int id = blockIdx.x;
  const float* in; f16* outp; int R, C;
  if (id < NT1) { in = w1; outp = o1; R = Ee; C = Ff; }
  else { id -= NT1; in = w2; outp = o2; R = Ff; C = Ee; }
  const int nx = C >> 5;
  cvtT_tile(in, outp, R, C, id % nx, id / nx, threadIdx.x);
}

// Fast fused QKV weight transpose-split (PROVEN r16/r18).
__global__ __launch_bounds__(256)
void cvtT_qkv(const float* __restrict__ wq, const float* __restrict__ wk,
              const float* __restrict__ wv, f16* __restrict__ out_h,
              f16* __restrict__ out_l)
{
  __shared__ float tile[64][33];
  const int z = blockIdx.z, sec = z >> 4, hh = z & 15;
  const float* in = (sec == 0) ? wq : (sec == 1) ? wk : wv;
  const size_t zi = (size_t)hh * Ee * Dd;
  const size_t zo = ((size_t)sec << 20) + (size_t)hh * Ee * Dd;
  const int c0 = blockIdx.x * 32, r0 = blockIdx.y * 64;
  const int tid = threadIdx.x;
  const int r = tid >> 2, c8 = (tid & 3) * 8;
  const float* src = &in[zi + (size_t)(r0 + r) * Dd + c0 + c8];
  float4 a = *(const float4*)src;
  float4 b = *(const float4*)(src + 4);
  tile[r][c8 + 0] = a.x; tile[r][c8 + 1] = a.y;
  tile[r][c8 + 2] = a.z; tile[r][c8 + 3] = a.w;
  tile[r][c8 + 4] = b.x; tile[r][c8 + 5] = b.y;
  tile[r][c8 + 6] = b.z; tile[r][c8 + 7] = b.w;
  __syncthreads();
  const int oc = tid >> 3, rr = (tid & 7) * 8;
  f16x8 oh, ol;
#pragma unroll
  for (int j = 0; j < 8; ++j) {
    float f = tile[rr + j][oc];
    f16 h = (f16)f;
    oh[j] = h;
    ol[j] = (f16)(f - (float)h);
  }
  const size_t ob = zo + (size_t)(c0 + oc) * Ee + r0 + rr;
  *(f16x8*)&out_h[ob] = oh;
  *(f16x8*)&out_l[ob] = ol;
}

// ---------------------------------------------------------------------------
extern "C" void kernel_launch(void* const* d_in, const int* in_sizes, int n_in,
                              void* d_out, int out_size, void* d_ws, size_t ws_size,
                              hipStream_t stream)
{
  const float* x     = (const float*)d_in[0];
  const float* mh_wq = (const float*)d_in[1];
  const float* mh_wk = (const float*)d_in[2];
  const float* mh_wv = (const float*)d_in[3];
  const float* mh_g  = (const float*)d_in[4];
  const float* mh_b  = (const float*)d_in[5];
  const float* ff_w1 = (const float*)d_in[6];
  const float* ff_b1 = (const float*)d_in[7];
  const float* ff_w2 = (const float*)d_in[8];
  const float* ff_b2 = (const float*)d_in[9];
  const float* ff_g  = (const float*)d_in[10];
  const float* ff_bb = (const float*)d_in[11];
  const float* lt_w  = (const float*)d_in[12];
  const float* lt_b  = (const float*)d_in[13];
  float* out = (float*)d_out;

  // ===== EXACT r11/r15/r16/r18 buffer layout (proven). 88 MB. =====
  const size_t ME = (size_t)Mm * Ee;   // 2M elements
  char* p = (char*)d_ws;
  auto alloc = [&](size_t bytes) { void* r = (void*)p; p += (bytes + 255) & ~(size_t)255; return r; };
  float* bufA  = (float*)alloc(ME * 4);                // 8 MB
  f16*   bufAh = (f16*)alloc(ME * 2);                  // 4 MB
  f16*   bufAl = (f16*)alloc(ME * 2);                  // 4 MB
  float* bufB  = (float*)alloc(ME * 4);                // 8 MB
  f16*   bufBh = (f16*)alloc(ME * 2);                  // 4 MB
  f16*   bufBl = (f16*)alloc(ME * 2);                  // 4 MB
  f16*   wt_h  = (f16*)alloc((size_t)Ff * Ee * 2);     // 8 MB (w1 / qkv-h / lt)
  f16*   wt_l  = (f16*)alloc((size_t)Ff * Ee * 2);     // 8 MB (w2 / qkv-l)
  float* reg   = (float*)alloc((size_t)10 * 1024 * 1024 * 4);  // 40 MB union
  f16*   qh_   = (f16*)reg;
  f16*   ql_   = qh_ + ME;
  f16*   kh_   = qh_ + 2 * ME;
  f16*   kl_   = qh_ + 3 * ME;
  f16*   vv_   = qh_ + 4 * ME;
  float* ob    = reg + 5 * 1024 * 1024;        // attn out (20..28 MB)
  f16*   hid   = (f16*)reg;                    // ff phase: [M,F] f16 = 16 MB
  float* tmp   = reg + 8 * 1024 * 1024;        // fp32 partial (32..40 MB)

  // mh: r18 dataflow; attn_ms now QBLK=128 (grid (4, B*H), 512 threads).
  auto mh = [&](int i, const float* srcF, const f16* srcH, const f16* srcL,
                float* dstF, f16* dstH, f16* dstL) {
    const size_t wo = (size_t)i * Hh * Ee * Dd;
    cvtT_qkv<<<dim3(Dd / 32, Ee / 64, 48), 256, 0, stream>>>(
        mh_wq + wo, mh_wk + wo, mh_wv + wo, wt_h, wt_l);
    gemm_qkv<<<dim3(24, Mm / 64), 256, 0, stream>>>(
        srcH, srcL, wt_h, wt_l, qh_, ql_, kh_, kl_, vv_);
    attn_ms<<<dim3(Tt / 128, Bb * Hh), 512, 0, stream>>>(qh_, ql_, kh_, kl_, vv_, ob);
    attn_ln_res<<<dim3(Mm * Hh / 4), 256, 0, stream>>>(
        ob, srcF, mh_g + (size_t)i * Hh * Dd, mh_b + (size_t)i * Hh * Dd, dstF, dstH, dstL);
  };
  // ff: byte-identical dataflow to r16/r18.
  auto ff = [&](int i, const float* srcF, const f16* srcH,
                float* dstF, f16* dstH, f16* dstL, float* tmp1) {
    cvtT_ff<<<dim3((Ff / 32) * (Ee / 64) + (Ee / 32) * (Ff / 64)), 256, 0, stream>>>(
        ff_w1 + (size_t)i * Ee * Ff, ff_w2 + (size_t)i * Ff * Ee, wt_h, wt_l);
    gemm_f16_128<<<dim3(Ff / 128, Mm / 128), 256, 0, stream>>>(
        srcH, wt_h, ff_b1 + (size_t)i * Ff, hid, Ff, Ee);
    gemm_f16_1p<false><<<dim3(Ee / 128, Mm / 64, 2), 256, 0, stream>>>(
        hid, nullptr, wt_l, tmp, tmp1, Ee, Ff);
    ff_ln_res<<<dim3(Mm), 256, 0, stream>>>(
        tmp, tmp1, ff_b2 + (size_t)i * Ee,
        srcF, ff_g + (size_t)i * Ee, ff_bb + (size_t)i * Ee, dstF, dstH, dstL);
  };

  // both branches' x-split in one launch
  split_act2<<<dim3(2 * ME / 1024), 256, 0, stream>>>(x, bufAh, bufAl, bufBh, bufBl);

  // out_one branch: ff(3, mh(4, mh(0, x)))   [bufB fp32 dead -> tmp1]
  mh(0, x, bufAh, bufAl, bufA, bufAh, bufAl);
  mh(4, bufA, bufAh, bufAl, bufA, bufAh, bufAl);
  ff(3, bufA, bufAh, bufA, bufAh, bufAl, bufB);

  // out_two branch: 3 encoder blocks then decoder  [bufA fp32 dead -> tmp1]
  mh(1, x, bufBh, bufBl, bufB, bufBh, bufBl);
  ff(0, bufB, bufBh, bufB, bufBh, bufBl, bufA);
  mh(2, bufB, bufBh, bufBl, bufB, bufBh, bufBl);
  ff(1, bufB, bufBh, bufB, bufBh, bufBl, bufA);
  mh(3, bufB, bufBh, bufBl, bufB, bufBh, bufBl);
  ff(2, bufB, bufBh, bufB, bufBh, bufBl, bufA);
  mh(4, bufB, bufBh, bufBl, bufB, bufBh, bufBl);
  ff(3, bufB, bufBh, bufB, bufBh, bufBl, bufA);

  // final: out = concat(A,B)@lt_w + lt_b, 1-pass f16, split-K=2 into dead bufs
  cvtT_f16<<<dim3((Ee / 32) * (2 * Ee / 64)), 256, 0, stream>>>(lt_w, wt_h, 2 * Ee, Ee);
  gemm_f16_1p<true><<<dim3(Ee / 128, Mm / 64, 2), 256, 0, stream>>>(
      bufAh, bufBh, wt_h, bufA, bufB, Ee, 2 * Ee);
  add2_bias<<<dim3(ME / 1024), 256, 0, stream>>>(bufA, bufB, lt_b, out);
}

// Round 20
// 967.957 us; speedup vs baseline: 1.1899x; 1.0103x over previous
//
#include <hip/hip_runtime.h>
#include <math.h>

#define Bb 4
#define Tt 512
#define Ee 1024
#define Hh 16
#define Dd 64
#define Ff 4096
#define Mm (Bb*Tt)   // 2048
static constexpr float EPS = 1e-5f;

typedef __attribute__((ext_vector_type(4))) float f32x4;
typedef _Float16 f16;
typedef __attribute__((ext_vector_type(8))) _Float16 f16x8;

// async global->LDS, 16B per lane. LDS dest must be lane-linear.
__device__ __forceinline__ void gload16(const void* g, void* l) {
  __builtin_amdgcn_global_load_lds(
      (const __attribute__((address_space(1))) unsigned int*)g,
      (__attribute__((address_space(3))) unsigned int*)l, 16, 0, 0);
}

// ---------------------------------------------------------------------------
// FF1: 1-pass fp16 GEMM, m97 structure (PROVEN r10-r19). 128x128, BK=32,
// single-buffer 16KB LDS, gload_lds staging. Bias+ReLU, f16 out.
// ---------------------------------------------------------------------------
__global__ __launch_bounds__(256)
void gemm_f16_128(const f16* __restrict__ A, const f16* __restrict__ W,
                  const float* __restrict__ bias,
                  f16* __restrict__ C, int ldc, int K)
{
  __shared__ f16 AS[128][32], BS[128][32];
  const int tid = threadIdx.x;
  const int lane = tid & 63, w = tid >> 6;
  const int wr = w >> 1, wc = w & 1;
  const int lhi = lane >> 4, llo = lane & 15;
  const int n0 = blockIdx.x * 128, m0 = blockIdx.y * 128;
  const int s_row = tid >> 2, s_ko = (tid & 3) * 8;

  f32x4 acc[4][4] = {};

  for (int k0 = 0; k0 < K; k0 += 32) {
#pragma unroll
    for (int i = 0; i < 2; ++i) {
      const int row = s_row + i * 64;
      gload16(&A[(size_t)(m0 + row) * K + k0 + s_ko], &AS[row][s_ko]);
      gload16(&W[(size_t)(n0 + row) * K + k0 + s_ko], &BS[row][s_ko]);
    }
    __syncthreads();
    f16x8 af[4], bf[4];
#pragma unroll
    for (int f = 0; f < 4; ++f) {
      af[f] = *(const f16x8*)&AS[wr * 64 + f * 16 + llo][lhi * 8];
      bf[f] = *(const f16x8*)&BS[wc * 64 + f * 16 + llo][lhi * 8];
    }
#pragma unroll
    for (int m = 0; m < 4; ++m)
#pragma unroll
      for (int n = 0; n < 4; ++n)
        acc[m][n] = __builtin_amdgcn_mfma_f32_16x16x32_f16(af[m], bf[n], acc[m][n], 0, 0, 0);
    __syncthreads();
  }

#pragma unroll
  for (int n = 0; n < 4; ++n) {
    const int col = n0 + wc * 64 + n * 16 + llo;
    const float bv = bias[col];
#pragma unroll
    for (int m = 0; m < 4; ++m) {
      const int rbase = m0 + wr * 64 + m * 16 + lhi * 4;
#pragma unroll
      for (int j = 0; j < 4; ++j) {
        float v = fmaxf(acc[m][n][j] + bv, 0.f);
        C[(size_t)(rbase + j) * ldc + col] = (f16)v;
      }
    }
  }
}

// ---------------------------------------------------------------------------
// 1-pass fp16 GEMM, 64x128 dbuf (PROVEN r10-r19): FF2 (SPLITK) / final.
// ---------------------------------------------------------------------------
template<bool CONCAT>
__global__ __launch_bounds__(256)
void gemm_f16_1p(const f16* __restrict__ A, const f16* __restrict__ A2,
                 const f16* __restrict__ W,
                 float* __restrict__ Cf, float* __restrict__ Cf1,
                 int ldc, int K)
{
  __shared__ f16 AS[2][64][32], BS[2][128][32];
  const int tid = threadIdx.x;
  const int lane = tid & 63, w = tid >> 6;
  const int wr = w >> 1, wc = w & 1;
  const int lhi = lane >> 4, llo = lane & 15;
  const int n0 = blockIdx.x * 128;
  const int m0 = blockIdx.y * 64;
  const int half = K >> 1;
  const int kbeg = blockIdx.z * half;
  const int nt = half / 32;
  if (blockIdx.z == 1) Cf = Cf1;

  const int s_row = tid >> 2, s_ko = (tid & 3) * 8;

  auto stage = [&](int k0, int buf) {
    const int gk = k0 + s_ko;
    const f16* s = A;
    size_t g;
    if (CONCAT) {
      if (gk < Ee) { g = (size_t)(m0 + s_row) * Ee + gk; }
      else { g = (size_t)(m0 + s_row) * Ee + (gk - Ee); s = A2; }
    } else {
      g = (size_t)(m0 + s_row) * K + gk;
    }
    gload16(&s[g], &AS[buf][s_row][s_ko]);
#pragma unroll
    for (int i = 0; i < 2; ++i)
      gload16(&W[(size_t)(n0 + s_row + i * 64) * K + gk], &BS[buf][s_row + i * 64][s_ko]);
  };

  f32x4 acc[2][4] = {};
  stage(kbeg, 0);
  __syncthreads();
  int cur = 0;
  for (int t = 0; t < nt; ++t) {
    if (t + 1 < nt) stage(kbeg + (t + 1) * 32, cur ^ 1);
    f16x8 af[2], bf[4];
#pragma unroll
    for (int m = 0; m < 2; ++m)
      af[m] = *(const f16x8*)&AS[cur][wr * 32 + m * 16 + llo][lhi * 8];
#pragma unroll
    for (int n = 0; n < 4; ++n)
      bf[n] = *(const f16x8*)&BS[cur][wc * 64 + n * 16 + llo][lhi * 8];
#pragma unroll
    for (int m = 0; m < 2; ++m)
#pragma unroll
      for (int n = 0; n < 4; ++n)
        acc[m][n] = __builtin_amdgcn_mfma_f32_16x16x32_f16(af[m], bf[n], acc[m][n], 0, 0, 0);
    __syncthreads();
    cur ^= 1;
  }

#pragma unroll
  for (int n = 0; n < 4; ++n) {
    const int col = n0 + wc * 64 + n * 16 + llo;
#pragma unroll
    for (int m = 0; m < 2; ++m) {
      const int rbase = m0 + wr * 32 + m * 16 + lhi * 4;
#pragma unroll
      for (int j = 0; j < 4; ++j)
        Cf[(size_t)(rbase + j) * ldc + col] = acc[m][n][j];
    }
  }
}

// ---------------------------------------------------------------------------
// QKV projection (PROVEN r11-r19): 64x128 dbuf, grid.x=24, sec = bx>>3.
// Q,K: 3-pass f16 (h,l) -> split (h,l) out. V: 1-pass -> plain f16 out.
// ---------------------------------------------------------------------------
__global__ __launch_bounds__(256)
void gemm_qkv(const f16* __restrict__ Ah_g, const f16* __restrict__ Al_g,
              const f16* __restrict__ Wh, const f16* __restrict__ Wl,
              f16* __restrict__ Qh, f16* __restrict__ Ql,
              f16* __restrict__ Kh, f16* __restrict__ Kl,
              f16* __restrict__ Vv)
{
  __shared__ f16 AhS[2][64][32], AlS[2][64][32];
  __shared__ f16 BhS[2][128][32], BlS[2][128][32];
  const int tid = threadIdx.x;
  const int lane = tid & 63, w = tid >> 6;
  const int wr = w >> 1, wc = w & 1;
  const int lhi = lane >> 4, llo = lane & 15;
  const int sec = blockIdx.x >> 3;
  const bool three = (sec < 2);
  const int n0 = (blockIdx.x & 7) * 128;
  Wh += (size_t)sec << 20;
  Wl += (size_t)sec << 20;
  const int m0 = blockIdx.y * 64;
  const int s_row = tid >> 2, s_ko = (tid & 3) * 8;

  auto stage = [&](int k0, int buf) {
    const size_t g = (size_t)(m0 + s_row) * Ee + k0 + s_ko;
    gload16(&Ah_g[g], &AhS[buf][s_row][s_ko]);
    if (three) gload16(&Al_g[g], &AlS[buf][s_row][s_ko]);
#pragma unroll
    for (int i = 0; i < 2; ++i) {
      size_t gb = (size_t)(n0 + s_row + i * 64) * Ee + k0 + s_ko;
      gload16(&Wh[gb], &BhS[buf][s_row + i * 64][s_ko]);
      if (three) gload16(&Wl[gb], &BlS[buf][s_row + i * 64][s_ko]);
    }
  };

  f32x4 acc[2][4] = {};
  stage(0, 0);
  __syncthreads();
  int cur = 0;
  for (int t = 0; t < Ee / 32; ++t) {
    if (t + 1 < Ee / 32) stage((t + 1) * 32, cur ^ 1);
    f16x8 ah[2], bh[4];
#pragma unroll
    for (int m = 0; m < 2; ++m)
      ah[m] = *(const f16x8*)&AhS[cur][wr * 32 + m * 16 + llo][lhi * 8];
#pragma unroll
    for (int n = 0; n < 4; ++n)
      bh[n] = *(const f16x8*)&BhS[cur][wc * 64 + n * 16 + llo][lhi * 8];
    if (three) {
      f16x8 al[2], bl[4];
#pragma unroll
      for (int m = 0; m < 2; ++m)
        al[m] = *(const f16x8*)&AlS[cur][wr * 32 + m * 16 + llo][lhi * 8];
#pragma unroll
      for (int n = 0; n < 4; ++n)
        bl[n] = *(const f16x8*)&BlS[cur][wc * 64 + n * 16 + llo][lhi * 8];
#pragma unroll
      for (int m = 0; m < 2; ++m)
#pragma unroll
        for (int n = 0; n < 4; ++n) {
          acc[m][n] = __builtin_amdgcn_mfma_f32_16x16x32_f16(ah[m], bh[n], acc[m][n], 0, 0, 0);
          acc[m][n] = __builtin_amdgcn_mfma_f32_16x16x32_f16(ah[m], bl[n], acc[m][n], 0, 0, 0);
          acc[m][n] = __builtin_amdgcn_mfma_f32_16x16x32_f16(al[m], bh[n], acc[m][n], 0, 0, 0);
        }
    } else {
#pragma unroll
      for (int m = 0; m < 2; ++m)
#pragma unroll
        for (int n = 0; n < 4; ++n)
          acc[m][n] = __builtin_amdgcn_mfma_f32_16x16x32_f16(ah[m], bh[n], acc[m][n], 0, 0, 0);
    }
    __syncthreads();
    cur ^= 1;
  }

#pragma unroll
  for (int n = 0; n < 4; ++n) {
    const int col = n0 + wc * 64 + n * 16 + llo;
#pragma unroll
    for (int m = 0; m < 2; ++m) {
      const int rbase = m0 + wr * 32 + m * 16 + lhi * 4;
#pragma unroll
      for (int j = 0; j < 4; ++j) {
        const float v = acc[m][n][j];
        const size_t idx = (size_t)(rbase + j) * Ee + col;
        if (sec == 0) {
          f16 h = (f16)v;
          Qh[idx] = h;
          Ql[idx] = (f16)(v - (float)h);
        } else if (sec == 1) {
          f16 h = (f16)v;
          Kh[idx] = h;
          Kl[idx] = (f16)(v - (float)h);
        } else {
          Vv[idx] = (f16)v;
        }
      }
    }
  }
}

// ---------------------------------------------------------------------------
// Split-f16 MFMA flash attention, causal, QBLK=128 (PROVEN r19 math/order).
// NEW (r20): double-buffered K/V staging (gemm_f16_1p's proven dbuf pattern).
// LDS 72KB — grid is 1 block/CU so no occupancy cost; hides tile-load latency.
// ---------------------------------------------------------------------------
__global__ __launch_bounds__(512)
void attn_ms(const f16* __restrict__ Qh_g, const f16* __restrict__ Ql_g,
             const f16* __restrict__ Kh_g, const f16* __restrict__ Kl_g,
             const f16* __restrict__ Vv_g, float* __restrict__ O)
{
  __shared__ f16 Ksh[2][64][72], Ksl[2][64][72];   // [buf][s][d]
  __shared__ f16 Vs[2][64][72];                    // [buf][d][s] (transposed)
  __shared__ f16 Pw[8][16][72];                    // per-wave P [q_local][s]
  const int tid = threadIdx.x;
  const int lane = tid & 63, w = tid >> 6;   // w in 0..7
  const int lhi = lane >> 4, llo = lane & 15;
  const int q0 = blockIdx.x * 128;
  const int bh = blockIdx.y;
  const size_t base = (size_t)(bh >> 4) * Tt * Ee + (size_t)(bh & 15) * Dd;

  f16x8 qfh[2], qfl[2];
#pragma unroll
  for (int ks = 0; ks < 2; ++ks) {
    const size_t qoff = base + (size_t)(q0 + w * 16 + llo) * Ee + ks * 32 + lhi * 8;
    qfh[ks] = *(const f16x8*)&Qh_g[qoff];
    qfl[ks] = *(const f16x8*)&Ql_g[qoff];
  }

  // 512-thread staging of one 64x64 K/V tile into buffer `buf`.
  const int st_row = tid >> 3, st_d0 = (tid & 7) * 8;
  auto stage = [&](int s0, int buf) {
    const size_t g = base + (size_t)(s0 + st_row) * Ee + st_d0;
    f16x8 kh = *(const f16x8*)&Kh_g[g];
    f16x8 kl = *(const f16x8*)&Kl_g[g];
    f16x8 vf = *(const f16x8*)&Vv_g[g];
    *(f16x8*)&Ksh[buf][st_row][st_d0] = kh;
    *(f16x8*)&Ksl[buf][st_row][st_d0] = kl;
#pragma unroll
    for (int j = 0; j < 8; ++j) Vs[buf][st_d0 + j][st_row] = vf[j];
  };

  f32x4 oacc[4] = {};
  float m_run[4], l_run[4];
#pragma unroll
  for (int j = 0; j < 4; ++j) { m_run[j] = -INFINITY; l_run[j] = 0.f; }

  const int s_end = q0 + 64;   // last tile start needed by rows q0..q0+127
  stage(0, 0);
  __syncthreads();
  int cur = 0;
  for (int s0 = 0; s0 <= s_end; s0 += 64) {
    if (s0 + 64 <= s_end) stage(s0 + 64, cur ^ 1);

    // S = Q K^T (3-pass split)
    f32x4 sacc[4] = {};
#pragma unroll
    for (int ks = 0; ks < 2; ++ks)
#pragma unroll
      for (int n = 0; n < 4; ++n) {
        f16x8 kfh = *(const f16x8*)&Ksh[cur][n * 16 + llo][ks * 32 + lhi * 8];
        f16x8 kfl = *(const f16x8*)&Ksl[cur][n * 16 + llo][ks * 32 + lhi * 8];
        sacc[n] = __builtin_amdgcn_mfma_f32_16x16x32_f16(qfh[ks], kfh, sacc[n], 0, 0, 0);
        sacc[n] = __builtin_amdgcn_mfma_f32_16x16x32_f16(qfh[ks], kfl, sacc[n], 0, 0, 0);
        sacc[n] = __builtin_amdgcn_mfma_f32_16x16x32_f16(qfl[ks], kfh, sacc[n], 0, 0, 0);
      }

    // causal mask: this wave's rows are q0+w*16 .. q0+w*16+15.
    if (s0 + 64 > q0 + w * 16) {
#pragma unroll
      for (int n = 0; n < 4; ++n)
#pragma unroll
        for (int j = 0; j < 4; ++j)
          if (s0 + n * 16 + llo > q0 + w * 16 + lhi * 4 + j) sacc[n][j] = -INFINITY;
    }

    float scj[4];
#pragma unroll
    for (int j = 0; j < 4; ++j) {
      float mt = fmaxf(fmaxf(sacc[0][j], sacc[1][j]), fmaxf(sacc[2][j], sacc[3][j]));
#pragma unroll
      for (int off = 1; off < 16; off <<= 1) mt = fmaxf(mt, __shfl_xor(mt, off));
      float mn = fmaxf(m_run[j], mt);
      scj[j] = __expf(m_run[j] - mn);
      m_run[j] = mn;
      float rs = 0.f;
#pragma unroll
      for (int n = 0; n < 4; ++n) {
        float pp = __expf(sacc[n][j] - mn);
        sacc[n][j] = pp;
        rs += pp;
      }
#pragma unroll
      for (int off = 1; off < 16; off <<= 1) rs += __shfl_xor(rs, off);
      l_run[j] = l_run[j] * scj[j] + rs;
    }

#pragma unroll
    for (int n = 0; n < 4; ++n)
#pragma unroll
      for (int j = 0; j < 4; ++j)
        Pw[w][lhi * 4 + j][n * 16 + llo] = (f16)sacc[n][j];
#pragma unroll
    for (int df = 0; df < 4; ++df)
#pragma unroll
      for (int j = 0; j < 4; ++j)
        oacc[df][j] *= scj[j];

#pragma unroll
    for (int ks = 0; ks < 2; ++ks) {
      f16x8 pf = *(const f16x8*)&Pw[w][llo][ks * 32 + lhi * 8];
#pragma unroll
      for (int df = 0; df < 4; ++df) {
        f16x8 vfr = *(const f16x8*)&Vs[cur][df * 16 + llo][ks * 32 + lhi * 8];
        oacc[df] = __builtin_amdgcn_mfma_f32_16x16x32_f16(pf, vfr, oacc[df], 0, 0, 0);
      }
    }
    __syncthreads();
    cur ^= 1;
  }

#pragma unroll
  for (int j = 0; j < 4; ++j) {
    float inv = 1.f / l_run[j];
#pragma unroll
    for (int df = 0; df < 4; ++df)
      O[base + (size_t)(q0 + w * 16 + lhi * 4 + j) * Ee + df * 16 + llo] =
          oacc[df][j] * inv;
  }
}

// ---------------------------------------------------------------------------
// Per-head LN over D=64 + residual (PROVEN r11-r19); fp32 + (h,l) f16.
// ---------------------------------------------------------------------------
__global__ __launch_bounds__(256)
void attn_ln_res(const float* __restrict__ O, const float* Yin,
                 const float* __restrict__ g, const float* __restrict__ bta,
                 float* Yout, f16* __restrict__ Yh, f16* __restrict__ Yl)
{
  const int tid = threadIdx.x;
  const int w = (blockIdx.x << 2) + (tid >> 6);
  const int lane = tid & 63;
  const int m = w >> 4;
  const int h = w & 15;
  const size_t idx = (size_t)m * Ee + h * Dd + lane;
  float x = O[idx];
  float s = x, s2 = x * x;
#pragma unroll
  for (int off = 1; off < 64; off <<= 1) {
    s  += __shfl_xor(s, off);
    s2 += __shfl_xor(s2, off);
  }
  float mean = s * (1.f / 64.f);
  float var  = s2 * (1.f / 64.f) - mean * mean;
  float inv  = rsqrtf(var + EPS);
  float r = Yin[idx] + (x - mean) * inv * g[h * Dd + lane] + bta[h * Dd + lane];
  Yout[idx] = r;
  f16 hh = (f16)r;
  Yh[idx] = hh;
  Yl[idx] = (f16)(r - (float)hh);
}

// ---------------------------------------------------------------------------
// Row LN over E=1024 + residual (PROVEN r11-r19). Input = T0 + T1 + bias.
// ---------------------------------------------------------------------------
__global__ __launch_bounds__(256)
void ff_ln_res(const float* __restrict__ T0, const float* __restrict__ T1,
               const float* __restrict__ b2,
               const float* Yin, const float* __restrict__ g,
               const float* __restrict__ bb,
               float* Yout, f16* __restrict__ Yh, f16* __restrict__ Yl)
{
  __shared__ float red[8];
  const int m = blockIdx.x;
  const int tid = threadIdx.x;
  const size_t basep = (size_t)m * Ee;
  float4 xa = *(const float4*)&T0[basep + (tid << 2)];
  float4 xb = *(const float4*)&T1[basep + (tid << 2)];
  float4 bv2 = *(const float4*)&b2[tid << 2];
  float xv[4] = {xa.x + xb.x + bv2.x, xa.y + xb.y + bv2.y,
                 xa.z + xb.z + bv2.z, xa.w + xb.w + bv2.w};
  float s  = xv[0] + xv[1] + xv[2] + xv[3];
  float s2 = xv[0]*xv[0] + xv[1]*xv[1] + xv[2]*xv[2] + xv[3]*xv[3];
#pragma unroll
  for (int off = 1; off < 64; off <<= 1) {
    s  += __shfl_xor(s, off);
    s2 += __shfl_xor(s2, off);
  }
  const int wid = tid >> 6;
  if ((tid & 63) == 0) { red[wid] = s; red[4 + wid] = s2; }
  __syncthreads();
  s  = red[0] + red[1] + red[2] + red[3];
  s2 = red[4] + red[5] + red[6] + red[7];
  float mean = s * (1.f / Ee);
  float var  = s2 * (1.f / Ee) - mean * mean;
  float inv  = rsqrtf(var + EPS);
  float4 y  = *(const float4*)&Yin[basep + (tid << 2)];
  float4 gg = *(const float4*)&g[tid << 2];
  float4 bv = *(const float4*)&bb[tid << 2];
  float gga[4] = {gg.x, gg.y, gg.z, gg.w};
  float bva[4] = {bv.x, bv.y, bv.z, bv.w};
  float ya[4] = {y.x, y.y, y.z, y.w};
  float o[4];
#pragma unroll
  for (int j = 0; j < 4; ++j) {
    o[j] = ya[j] + (xv[j] - mean) * inv * gga[j] + bva[j];
    f16 hh = (f16)o[j];
    Yh[basep + (tid << 2) + j] = hh;
    Yl[basep + (tid << 2) + j] = (f16)(o[j] - (float)hh);
  }
  *(float4*)&Yout[basep + (tid << 2)] = *(float4*)o;
}

// out = p0 + p1 + bias (final linear reduce)
__global__ __launch_bounds__(256)
void add2_bias(const float* __restrict__ p0, const float* __restrict__ p1,
               const float* __restrict__ b, float* __restrict__ out)
{
  const size_t i = ((size_t)blockIdx.x * 256 + threadIdx.x) * 4;
  const int col = (int)(i & (Ee - 1));
  float4 a = *(const float4*)&p0[i];
  float4 c = *(const float4*)&p1[i];
  float4 bb = *(const float4*)&b[col];
  float4 o;
  o.x = a.x + c.x + bb.x; o.y = a.y + c.y + bb.y;
  o.z = a.z + c.z + bb.z; o.w = a.w + c.w + bb.w;
  *(float4*)&out[i] = o;
}

// fp32 -> (hi,lo) f16 split for BOTH branches in one launch (PROVEN r15-r19).
__global__ __launch_bounds__(256)
void split_act2(const float* __restrict__ in,
                f16* __restrict__ oh1, f16* __restrict__ ol1,
                f16* __restrict__ oh2, f16* __restrict__ ol2)
{
  const size_t nb = gridDim.x >> 1;
  size_t bid = blockIdx.x;
  f16 *oh, *ol;
  if (bid < nb) { oh = oh1; ol = ol1; }
  else { bid -= nb; oh = oh2; ol = ol2; }
  const size_t i = (bid * 256 + threadIdx.x) * 4;
  float4 v = *(const float4*)&in[i];
  float f[4] = {v.x, v.y, v.z, v.w};
#pragma unroll
  for (int j = 0; j < 4; ++j) {
    f16 h = (f16)f[j];
    oh[i + j] = h;
    ol[i + j] = (f16)(f[j] - (float)h);
  }
}

// ---------------------------------------------------------------------------
// FAST transpose-convert (PROVEN r16-r19): fp32 [R][C] -> f16 [C][R].
// ---------------------------------------------------------------------------
__device__ __forceinline__ void cvtT_tile(const float* in, f16* outp,
                                          int R, int C, int tx, int ty, int tid)
{
  __shared__ float tile[64][33];
  const int c0 = tx * 32, r0 = ty * 64;
  const int r = tid >> 2, c8 = (tid & 3) * 8;
  const float* src = &in[(size_t)(r0 + r) * C + c0 + c8];
  float4 a = *(const float4*)src;
  float4 b = *(const float4*)(src + 4);
  tile[r][c8 + 0] = a.x; tile[r][c8 + 1] = a.y;
  tile[r][c8 + 2] = a.z; tile[r][c8 + 3] = a.w;
  tile[r][c8 + 4] = b.x; tile[r][c8 + 5] = b.y;
  tile[r][c8 + 6] = b.z; tile[r][c8 + 7] = b.w;
  __syncthreads();
  const int oc = tid >> 3, rr = (tid & 7) * 8;
  f16x8 o;
#pragma unroll
  for (int j = 0; j < 8; ++j) o[j] = (f16)tile[rr + j][oc];
  *(f16x8*)&outp[(size_t)(c0 + oc) * R + r0 + rr] = o;
}

__global__ __launch_bounds__(256)
void cvtT_f16(const float* __restrict__ in, f16* __restrict__ outp, int R, int C)
{
  const int nx = C >> 5;
  cvtT_tile(in, outp, R, C, blockIdx.x % nx, blockIdx.x / nx, threadIdx.x);
}

// Fused FF weight transpose (fast, PROVEN r16-r19).
__global__ __launch_bounds__(256)
void cvtT_ff(const float* __restrict__ w1, const float* __restrict__ w2,
             f16* __restrict__ o1, f16* __restrict__ o2)
{
  constexpr int NT1 = (Ff / 32) * (Ee / 64);   // 2048
  int id = blockIdx.x;
  const float* in; f16* outp; int R, C;
  if (id < NT1) { in = w1; outp = o1; R = Ee; C = Ff; }
  else { id -= NT1; in = w2; outp = o2; R = Ff; C = Ee; }
  const int nx = C >> 5;
  cvtT_tile(in, outp, R, C, id % nx, id / nx, threadIdx.x);
}

// Fast fused QKV weight transpose-split (PROVEN r16-r19).
__global__ __launch_bounds__(256)
void cvtT_qkv(const float* __restrict__ wq, const float* __restrict__ wk,
              const float* __restrict__ wv, f16* __restrict__ out_h,
              f16* __restrict__ out_l)
{
  __shared__ float tile[64][33];
  const int z = blockIdx.z, sec = z >> 4, hh = z & 15;
  const float* in = (sec == 0) ? wq : (sec == 1) ? wk : wv;
  const size_t zi = (size_t)hh * Ee * Dd;
  const size_t zo = ((size_t)sec << 20) + (size_t)hh * Ee * Dd;
  const int c0 = blockIdx.x * 32, r0 = blockIdx.y * 64;
  const int tid = threadIdx.x;
  const int r = tid >> 2, c8 = (tid & 3) * 8;
  const float* src = &in[zi + (size_t)(r0 + r) * Dd + c0 + c8];
  float4 a = *(const float4*)src;
  float4 b = *(const float4*)(src + 4);
  tile[r][c8 + 0] = a.x; tile[r][c8 + 1] = a.y;
  tile[r][c8 + 2] = a.z; tile[r][c8 + 3] = a.w;
  tile[r][c8 + 4] = b.x; tile[r][c8 + 5] = b.y;
  tile[r][c8 + 6] = b.z; tile[r][c8 + 7] = b.w;
  __syncthreads();
  const int oc = tid >> 3, rr = (tid & 7) * 8;
  f16x8 oh, ol;
#pragma unroll
  for (int j = 0; j < 8; ++j) {
    float f = tile[rr + j][oc];
    f16 h = (f16)f;
    oh[j] = h;
    ol[j] = (f16)(f - (float)h);
  }
  const size_t ob = zo + (size_t)(c0 + oc) * Ee + r0 + rr;
  *(f16x8*)&out_h[ob] = oh;
  *(f16x8*)&out_l[ob] = ol;
}

// ---------------------------------------------------------------------------
extern "C" void kernel_launch(void* const* d_in, const int* in_sizes, int n_in,
                              void* d_out, int out_size, void* d_ws, size_t ws_size,
                              hipStream_t stream)
{
  const float* x     = (const float*)d_in[0];
  const float* mh_wq = (const float*)d_in[1];
  const float* mh_wk = (const float*)d_in[2];
  const float* mh_wv = (const float*)d_in[3];
  const float* mh_g  = (const float*)d_in[4];
  const float* mh_b  = (const float*)d_in[5];
  const float* ff_w1 = (const float*)d_in[6];
  const float* ff_b1 = (const float*)d_in[7];
  const float* ff_w2 = (const float*)d_in[8];
  const float* ff_b2 = (const float*)d_in[9];
  const float* ff_g  = (const float*)d_in[10];
  const float* ff_bb = (const float*)d_in[11];
  const float* lt_w  = (const float*)d_in[12];
  const float* lt_b  = (const float*)d_in[13];
  float* out = (float*)d_out;

  // ===== EXACT r11/r15/r16/r18/r19 buffer layout (proven). 88 MB. =====
  const size_t ME = (size_t)Mm * Ee;   // 2M elements
  char* p = (char*)d_ws;
  auto alloc = [&](size_t bytes) { void* r = (void*)p; p += (bytes + 255) & ~(size_t)255; return r; };
  float* bufA  = (float*)alloc(ME * 4);                // 8 MB
  f16*   bufAh = (f16*)alloc(ME * 2);                  // 4 MB
  f16*   bufAl = (f16*)alloc(ME * 2);                  // 4 MB
  float* bufB  = (float*)alloc(ME * 4);                // 8 MB
  f16*   bufBh = (f16*)alloc(ME * 2);                  // 4 MB
  f16*   bufBl = (f16*)alloc(ME * 2);                  // 4 MB
  f16*   wt_h  = (f16*)alloc((size_t)Ff * Ee * 2);     // 8 MB (w1 / qkv-h / lt)
  f16*   wt_l  = (f16*)alloc((size_t)Ff * Ee * 2);     // 8 MB (w2 / qkv-l)
  float* reg   = (float*)alloc((size_t)10 * 1024 * 1024 * 4);  // 40 MB union
  f16*   qh_   = (f16*)reg;
  f16*   ql_   = qh_ + ME;
  f16*   kh_   = qh_ + 2 * ME;
  f16*   kl_   = qh_ + 3 * ME;
  f16*   vv_   = qh_ + 4 * ME;
  float* ob    = reg + 5 * 1024 * 1024;        // attn out (20..28 MB)
  f16*   hid   = (f16*)reg;                    // ff phase: [M,F] f16 = 16 MB
  float* tmp   = reg + 8 * 1024 * 1024;        // fp32 partial (32..40 MB)

  // mh: r19 dataflow; attn_ms now K/V double-buffered.
  auto mh = [&](int i, const float* srcF, const f16* srcH, const f16* srcL,
                float* dstF, f16* dstH, f16* dstL) {
    const size_t wo = (size_t)i * Hh * Ee * Dd;
    cvtT_qkv<<<dim3(Dd / 32, Ee / 64, 48), 256, 0, stream>>>(
        mh_wq + wo, mh_wk + wo, mh_wv + wo, wt_h, wt_l);
    gemm_qkv<<<dim3(24, Mm / 64), 256, 0, stream>>>(
        srcH, srcL, wt_h, wt_l, qh_, ql_, kh_, kl_, vv_);
    attn_ms<<<dim3(Tt / 128, Bb * Hh), 512, 0, stream>>>(qh_, ql_, kh_, kl_, vv_, ob);
    attn_ln_res<<<dim3(Mm * Hh / 4), 256, 0, stream>>>(
        ob, srcF, mh_g + (size_t)i * Hh * Dd, mh_b + (size_t)i * Hh * Dd, dstF, dstH, dstL);
  };
  // ff: byte-identical dataflow to r16-r19.
  auto ff = [&](int i, const float* srcF, const f16* srcH,
                float* dstF, f16* dstH, f16* dstL, float* tmp1) {
    cvtT_ff<<<dim3((Ff / 32) * (Ee / 64) + (Ee / 32) * (Ff / 64)), 256, 0, stream>>>(
        ff_w1 + (size_t)i * Ee * Ff, ff_w2 + (size_t)i * Ff * Ee, wt_h, wt_l);
    gemm_f16_128<<<dim3(Ff / 128, Mm / 128), 256, 0, stream>>>(
        srcH, wt_h, ff_b1 + (size_t)i * Ff, hid, Ff, Ee);
    gemm_f16_1p<false><<<dim3(Ee / 128, Mm / 64, 2), 256, 0, stream>>>(
        hid, nullptr, wt_l, tmp, tmp1, Ee, Ff);
    ff_ln_res<<<dim3(Mm), 256, 0, stream>>>(
        tmp, tmp1, ff_b2 + (size_t)i * Ee,
        srcF, ff_g + (size_t)i * Ee, ff_bb + (size_t)i * Ee, dstF, dstH, dstL);
  };

  // both branches' x-split in one launch
  split_act2<<<dim3(2 * ME / 1024), 256, 0, stream>>>(x, bufAh, bufAl, bufBh, bufBl);

  // out_one branch: ff(3, mh(4, mh(0, x)))   [bufB fp32 dead -> tmp1]
  mh(0, x, bufAh, bufAl, bufA, bufAh, bufAl);
  mh(4, bufA, bufAh, bufAl, bufA, bufAh, bufAl);
  ff(3, bufA, bufAh, bufA, bufAh, bufAl, bufB);

  // out_two branch: 3 encoder blocks then decoder  [bufA fp32 dead -> tmp1]
  mh(1, x, bufBh, bufBl, bufB, bufBh, bufBl);
  ff(0, bufB, bufBh, bufB, bufBh, bufBl, bufA);
  mh(2, bufB, bufBh, bufBl, bufB, bufBh, bufBl);
  ff(1, bufB, bufBh, bufB, bufBh, bufBl, bufA);
  mh(3, bufB, bufBh, bufBl, bufB, bufBh, bufBl);
  ff(2, bufB, bufBh, bufB, bufBh, bufBl, bufA);
  mh(4, bufB, bufBh, bufBl, bufB, bufBh, bufBl);
  ff(3, bufB, bufBh, bufB, bufBh, bufBl, bufA);

  // final: out = concat(A,B)@lt_w + lt_b, 1-pass f16, split-K=2 into dead bufs
  cvtT_f16<<<dim3((Ee / 32) * (2 * Ee / 64)), 256, 0, stream>>>(lt_w, wt_h, 2 * Ee, Ee);
  gemm_f16_1p<true><<<dim3(Ee / 128, Mm / 64, 2), 256, 0, stream>>>(
      bufAh, bufBh, wt_h, bufA, bufB, Ee, 2 * Ee);
  add2_bias<<<dim3(ME / 1024), 256, 0, stream>>>(bufA, bufB, lt_b, out);
}